// Round 3
// baseline (3145.584 us; speedup 1.0000x reference)
//
#include <hip/hip_runtime.h>
#include <hip/hip_bf16.h>
#include <math.h>

typedef __attribute__((ext_vector_type(8))) short short8;
typedef __attribute__((ext_vector_type(4))) float floatx4;

#define DEVFN static __device__ __forceinline__

constexpr int B = 128, T = 256, H = 512;
constexpr int OUTW = 121;
// fxHL slot row layout (per batch row, per time slot), elems:
//   hi: [x(3) win(60) pad(1) h1(512) h2(512)] = 1088
//   lo: cols 0..575 only (x,win,h1)           = 576
constexpr int SLOTW = 1664;              // row stride in elems (hi 1088 + lo 576)
constexpr int LOOF  = 1088;              // lo region offset within row
constexpr int SLOTE = B * SLOTW;         // elems per time slot
constexpr int NSLOT = T + 2;
constexpr int NG  = 2048;                // 4*H gate rows (interleaved n' = hcol*4+gate)
constexpr int K1  = 576,  K1C = 18;
constexpr int K2  = 1088, K2C = 34;
constexpr int KW1P = 584, KW2P = 1096;   // LDS weight row pads

// ---- LDS offsets (bytes) ----
// G1 path. NOTE: hs/pp alias the Gsm region — window phase and GEMM phase are
// temporally disjoint (separated by barriers).
constexpr int O_WH1 = 0;                 // 32*584*2 = 37376
constexpr int O_WL1 = 37376;             // -> 74752
constexpr int O_W1S = 74752;             // 30*520*4 = 62400 -> 137152
constexpr int O_GSM = 137152;            // 32*65*4 = 8320 -> 145472
constexpr int O_HS  = 137152;            // 528*4 = 2112 (alias in Gsm)
constexpr int O_PP  = 139264;            // 240*4 = 960 (alias in Gsm)
constexpr int O_IPL = 145472;            // 30*4
constexpr int O_KL  = 145592;            // 10*4
constexpr int O_PHL = 145632;            // 64*4
constexpr int O_WAC = 145888;            // 240*4
constexpr int O_KPR = 146848;            // 10*4
constexpr int O_B1S = 146888;            // 30*4
constexpr int O_BIA = 147008;            // 32*4 -> 147136
constexpr int O_SENT = 147136;           // 64*60 fp32 = 15360 -> 162496
// G2 path:
constexpr int O_WH2 = 0;                 // 32*1096*2 = 70144
constexpr int O_WL2 = 70144;             // -> 140288
constexpr int O_GS2 = 140288;            // 8320 -> 148608
constexpr int O_BI2 = 148608;            // 128 -> 148736
constexpr int LDS_SZ = 162496;

DEVFN __hip_bfloat16 bhi(float v) { return __float2bfloat16(v); }
DEVFN __hip_bfloat16 blo(float v, __hip_bfloat16 h) { return __float2bfloat16(v - __bfloat162float(h)); }
DEVFN float bf2f(__hip_bfloat16 h) { return __bfloat162float(h); }
DEVFN unsigned short bbits(__hip_bfloat16 h) { union { __hip_bfloat16 h; unsigned short u; } c; c.h = h; return c.u; }
DEVFN unsigned int pack2(float a, float b) {
  return (unsigned int)bbits(bhi(a)) | ((unsigned int)bbits(bhi(b)) << 16);
}
DEVFN void ast(unsigned int* p, unsigned int v) {
  __hip_atomic_store(p, v, __ATOMIC_RELAXED, __HIP_MEMORY_SCOPE_AGENT);
}
DEVFN int ald(int* p) {
  return __hip_atomic_load(p, __ATOMIC_RELAXED, __HIP_MEMORY_SCOPE_AGENT);
}

// ---- 8-leaf tree-counter barriers ----
// Each barrier group = 64 blocks. Producers add to leaf (nt&7); each leaf on
// its own 128B line -> 8 serialized RMWs/line instead of 64. Consumers: 8
// threads each poll one leaf for >= 8*step.
DEVFN void waitcnt8(int* base, int target) {
  if (threadIdx.x < 8) {
    int* p = base + threadIdx.x * 32;
    int g = 0;
    while (ald(p) < target && g < (1 << 24)) { ++g; __builtin_amdgcn_s_sleep(1); }
  }
  asm volatile("" ::: "memory");
  __syncthreads();
}
// Producer: drain own stores (all waves), then one atomic increment to leaf.
DEVFN void cnt_add(int* leaf) {
  asm volatile("s_waitcnt vmcnt(0)" ::: "memory");
  __syncthreads();
  if (threadIdx.x == 0)
    (void)__hip_atomic_fetch_add(leaf, 1, __ATOMIC_RELAXED, __HIP_MEMORY_SCOPE_AGENT);
}

// ---------------- precompute ----------------
__global__ __launch_bounds__(256) void k_pre(
    const float* __restrict__ x, const float* __restrict__ h1h, const float* __restrict__ h2h,
    const float* __restrict__ Wihc, const float* __restrict__ Whhc, const float* __restrict__ bc,
    const float* __restrict__ Wihl, const float* __restrict__ Whhl, const float* __restrict__ bl,
    const float* __restrict__ W2,
    __hip_bfloat16* __restrict__ fxHL,
    __hip_bfloat16* __restrict__ wc1, __hip_bfloat16* __restrict__ wc1l,
    __hip_bfloat16* __restrict__ wc2, __hip_bfloat16* __restrict__ wc2l,
    __hip_bfloat16* __restrict__ w2b, float* __restrict__ bi1, float* __restrict__ bi2,
    int* __restrict__ ctl)
{
  int idx = blockIdx.x * 256 + threadIdx.x;
  const int nwc1 = NG * K1, nwc2 = NG * K2, nw2b = 128 * 512, nbi = 2 * NG;
  const int nfh = B * H, nxj = T * B, nctl = 2048;
  if (idx < nwc1) {
    int n = idx / K1, col = idx - n * K1;
    int src = (n & 3) * H + (n >> 2);
    float v = (col < 63) ? Wihc[src * 63 + col]
            : (col == 63 ? 0.f : Whhc[src * 512 + (col - 64)]);
    __hip_bfloat16 h = bhi(v);
    wc1[n * K1 + col] = h; wc1l[n * K1 + col] = blo(v, h);
    return;
  }
  idx -= nwc1;
  if (idx < nwc2) {
    int n = idx / K2, col = idx - n * K2;
    int src = (n & 3) * H + (n >> 2);
    float v;
    if (col < 63)       v = Wihl[src * 575 + col];
    else if (col == 63) v = 0.f;
    else if (col < 576) v = Wihl[src * 575 + (col - 1)];
    else                v = Whhl[src * 512 + (col - 576)];
    __hip_bfloat16 h = bhi(v);
    wc2[n * K2 + col] = h; wc2l[n * K2 + col] = blo(v, h);
    return;
  }
  idx -= nwc2;
  if (idx < nw2b) {
    int n = idx >> 9, col = idx & 511;
    w2b[idx] = bhi(n < OUTW ? W2[n * 512 + col] : 0.f);
    return;
  }
  idx -= nw2b;
  if (idx < nbi) {
    int n = idx & (NG - 1);
    int src = (n & 3) * H + (n >> 2);
    if (idx < NG) bi1[n] = bc[src]; else bi2[n] = bl[src];
    return;
  }
  idx -= nbi;
  if (idx < nfh) {  // slot0 h1 init (hi+lo)
    int b = idx >> 9, j = idx & 511;
    float v = h1h[idx];
    __hip_bfloat16 h = bhi(v);
    fxHL[b * SLOTW + 64 + j] = h;
    fxHL[b * SLOTW + LOOF + 64 + j] = blo(v, h);
    return;
  }
  idx -= nfh;
  if (idx < nfh) {  // slot1 h2 init (hi only)
    int b = idx >> 9, j = idx & 511;
    fxHL[(size_t)SLOTE + b * SLOTW + 576 + j] = bhi(h2h[idx]);
    return;
  }
  idx -= nfh;
  if (idx < nxj) {  // x cols {0,1} hi + lo zeros for slot t+1
    int t = idx >> 7, b = idx & 127;
    float x0 = x[(b * T + t) * 3 + 0], x1 = x[(b * T + t) * 3 + 1];
    unsigned int* ph = (unsigned int*)(fxHL + (size_t)(t + 1) * SLOTE + b * SLOTW);
    ph[0] = pack2(x0, x1);
    unsigned int* pl = (unsigned int*)(fxHL + (size_t)(t + 1) * SLOTE + b * SLOTW + LOOF);
    pl[0] = 0u;
    return;
  }
  idx -= nxj;
  if (idx < nctl) ctl[idx] = 0;
}

// ---------------- MFMA helper (A rows from global, W in LDS) ----------------
template <int KWP>
DEVFN void gemm3(int tid, const __hip_bfloat16* __restrict__ Aslot, int m0,
                 const __hip_bfloat16* __restrict__ Wh, const __hip_bfloat16* __restrict__ Wl,
                 int cbeg, int cend, floatx4& a0, floatx4& a1)
{
  const int lane = tid & 63, wv = tid >> 6;
  const int lm = lane & 15, lk = (lane >> 4) << 3;
  const __hip_bfloat16* Ar = Aslot + (size_t)(m0 + wv * 16 + lm) * SLOTW;
  const __hip_bfloat16* W0h = Wh + lm * KWP;
  const __hip_bfloat16* W1h = Wh + (16 + lm) * KWP;
  const __hip_bfloat16* W0l = Wl + lm * KWP;
  const __hip_bfloat16* W1l = Wl + (16 + lm) * KWP;
  #pragma unroll 4
  for (int c = cbeg; c < cend; ++c) {
    int col = c * 32 + lk;
    short8 va  = *(const short8*)(Ar + col);
    short8 ua  = *(const short8*)(Ar + LOOF + col);
    short8 vb0 = *(const short8*)(W0h + col);
    short8 vb1 = *(const short8*)(W1h + col);
    short8 ub0 = *(const short8*)(W0l + col);
    short8 ub1 = *(const short8*)(W1l + col);
    a0 = __builtin_amdgcn_mfma_f32_16x16x32_bf16(va, vb0, a0, 0, 0, 0);
    a1 = __builtin_amdgcn_mfma_f32_16x16x32_bf16(va, vb1, a1, 0, 0, 0);
    a0 = __builtin_amdgcn_mfma_f32_16x16x32_bf16(va, ub0, a0, 0, 0, 0);
    a1 = __builtin_amdgcn_mfma_f32_16x16x32_bf16(va, ub1, a1, 0, 0, 0);
    a0 = __builtin_amdgcn_mfma_f32_16x16x32_bf16(ua, vb0, a0, 0, 0, 0);
    a1 = __builtin_amdgcn_mfma_f32_16x16x32_bf16(ua, vb1, a1, 0, 0, 0);
  }
}

DEVFN void store_gsm(int tid, float* Gsm, floatx4 a0, floatx4 a1) {
  const int lane = tid & 63, wv = tid >> 6;
  const int lm = lane & 15, rr = (lane >> 4) << 2;
  #pragma unroll
  for (int r = 0; r < 4; ++r) {
    Gsm[lm * 65 + wv * 16 + rr + r]        = a0[r];
    Gsm[(16 + lm) * 65 + wv * 16 + rr + r] = a1[r];
  }
}

// ---------------- persistent fused kernel ----------------
__global__ __launch_bounds__(256, 1) void k_persist(
    __hip_bfloat16* __restrict__ fxHL,
    const __hip_bfloat16* __restrict__ wc1, const __hip_bfloat16* __restrict__ wc1l,
    const __hip_bfloat16* __restrict__ wc2, const __hip_bfloat16* __restrict__ wc2l,
    const float* __restrict__ bi1, const float* __restrict__ bi2,
    const float* __restrict__ c1init, const float* __restrict__ c2init,
    const float* __restrict__ xin, const float* __restrict__ sent,
    const float* __restrict__ W1, const float* __restrict__ b1,
    int* __restrict__ ctl,
    float* __restrict__ h1f, float* __restrict__ c1f,
    float* __restrict__ h2f, float* __restrict__ c2f)
{
  extern __shared__ char sm[];
  const int gid = blockIdx.x, tid = threadIdx.x;
  const int lane = tid & 63, wv = tid >> 6;
  const int lm = lane & 15, lk = (lane >> 4) << 3;

  if (gid < 128) {
    // ========== G1: window + lstm1 ==========
    const int nt1 = gid >> 1, mh = gid & 1;
    const int n0 = nt1 * 32, m0 = mh * 64;
    const int brow = mh * 64 + nt1;
    const int leaf = (nt1 & 7) * 32;
    int* hcnt = ctl + mh * 256;            // h1 step completion tree (8 leaves)
    int* wcnt = ctl + 512 + mh * 256;      // win publication tree
    __hip_bfloat16* smWh = (__hip_bfloat16*)(sm + O_WH1);
    __hip_bfloat16* smWl = (__hip_bfloat16*)(sm + O_WL1);
    float* smW1 = (float*)(sm + O_W1S);
    float* Gsm  = (float*)(sm + O_GSM);
    float* hs   = (float*)(sm + O_HS);   // aliases Gsm region (window phase only)
    float* pp   = (float*)(sm + O_PP);   // aliases Gsm region (window phase only)
    float* ipl  = (float*)(sm + O_IPL);
    float* kl   = (float*)(sm + O_KL);
    float* phl  = (float*)(sm + O_PHL);
    float* wac  = (float*)(sm + O_WAC);
    float* kpr  = (float*)(sm + O_KPR);
    float* b1s  = (float*)(sm + O_B1S);
    float* bia  = (float*)(sm + O_BIA);
    float* ssent = (float*)(sm + O_SENT);

    for (int i = tid; i < 32 * 72; i += 256) {
      int r = i / 72, c8 = (i - r * 72) * 8;
      *(short8*)(smWh + r * KW1P + c8) = *(const short8*)(wc1  + (size_t)(n0 + r) * K1 + c8);
      *(short8*)(smWl + r * KW1P + c8) = *(const short8*)(wc1l + (size_t)(n0 + r) * K1 + c8);
    }
    for (int i = tid; i < 30 * 512; i += 256) {
      int j = i >> 9, c = i & 511;
      smW1[j * 520 + (c >> 6) * 65 + (c & 63)] = W1[i];
    }
    for (int i = tid; i < 64 * 60; i += 256)
      ssent[i] = sent[(size_t)brow * 64 * 60 + i];   // fp32 — bf16 here fails c1f (R7)
    if (tid < 30) b1s[tid] = b1[tid];
    if (tid < 10) kpr[tid] = 0.f;
    if (tid < 32) bia[tid] = bi1[n0 + tid];
    __syncthreads();

    float creg[2];
    {
      int ml = tid >> 2, ppi = tid & 3;
      creg[0] = c1init[(m0 + ml) * H + nt1 * 8 + 2 * ppi + 0];
      creg[1] = c1init[(m0 + ml) * H + nt1 * 8 + 2 * ppi + 1];
    }

    const __hip_bfloat16* W0h = smWh + lm * KW1P;
    const __hip_bfloat16* W1h = smWh + (16 + lm) * KW1P;
    const __hip_bfloat16* W0l = smWl + lm * KW1P;
    const __hip_bfloat16* W1l = smWl + (16 + lm) * KW1P;

    for (int t = 0; t < T; ++t) {
      __hip_bfloat16* S1 = fxHL + (size_t)(t + 1) * SLOTE;
      __hip_bfloat16* S0 = fxHL + (size_t)t * SLOTE;

      waitcnt8(hcnt, 8 * t);   // all same-half h1_{t-1} published

      // ---- own h-row loads + x scalar (only loads before win publish:
      //      keeps the mid-step vmcnt(0) drain down to ~stores-only) ----
      const __hip_bfloat16* wrow = S0 + (size_t)brow * SLOTW;
      __hip_bfloat16 a0h = wrow[64 + tid];
      __hip_bfloat16 a0l = wrow[LOOF + 64 + tid];
      __hip_bfloat16 a1h = wrow[64 + 256 + tid];
      __hip_bfloat16 a1l = wrow[LOOF + 64 + 256 + tid];
      float x2v = xin[(brow * T + t) * 3 + 2];
      hs[(tid >> 6) * 66 + (tid & 63)] = bf2f(a0h) + bf2f(a0l);
      hs[((tid + 256) >> 6) * 66 + (tid & 63)] = bf2f(a1h) + bf2f(a1l);
      __syncthreads();

      // ---- window compute (LDS only) ----
      if (tid < 240) {
        int j = tid >> 3, p = tid & 7;
        const float* wp = smW1 + j * 520 + p * 65;
        const float* hv = hs + p * 66;
        float s = 0.f;
        #pragma unroll 8
        for (int k = 0; k < 64; ++k) s += hv[k] * wp[k];
        pp[tid] = s;
      }
      __syncthreads();
      if (tid < 30) {       // merged ip-exp + kappa stage (wave 0 only)
        float s = b1s[tid];
        #pragma unroll
        for (int p = 0; p < 8; ++p) s += pp[tid * 8 + p];
        float e = expf(s);
        ipl[tid] = e;
        if (tid >= 20) {
          float kap = e - kpr[tid - 20];
          kpr[tid - 20] = kap; kl[tid - 20] = kap;
        }
      }
      // wave-local hand-off (both stages wave 0): LDS writes complete, no
      // block barrier needed; "memory" clobber pins the ds op order.
      asm volatile("s_waitcnt lgkmcnt(0)" ::: "memory");
      if (tid < 64) {
        float u = (float)(tid + 1);
        float acc = 0.f;
        #pragma unroll
        for (int k = 0; k < 10; ++k) {
          float d = kl[k] - u;
          acc += ipl[k] * expf(-ipl[10 + k] * d * d);
        }
        phl[tid] = acc;
      }
      __syncthreads();
      if (tid < 240) {
        int c = tid >> 2, p = tid & 3;
        float acc = 0.f;
        #pragma unroll
        for (int s0 = 0; s0 < 16; ++s0)
          acc += phl[p * 16 + s0] * ssent[(p * 16 + s0) * 60 + c];
        wac[tid] = acc;
      }
      __syncthreads();
      if (tid < 31) {  // publish win; winv reduction folded in (8 adds/thread)
        int d = 1 + tid;
        int c0 = 2 * d, c1 = 2 * d + 1;
        float v0, v1;
        if (c0 == 2) v0 = x2v;
        else { int j = (c0 - 3) * 4; v0 = wac[j] + wac[j + 1] + wac[j + 2] + wac[j + 3]; }
        if (c1 == 63) v1 = 0.f;
        else { int j = (c1 - 3) * 4; v1 = wac[j] + wac[j + 1] + wac[j + 2] + wac[j + 3]; }
        __hip_bfloat16 h0 = bhi(v0), h1v = bhi(v1);
        unsigned int* prow = (unsigned int*)(S1 + (size_t)brow * SLOTW);
        ast(prow + d, (unsigned int)bbits(h0) | ((unsigned int)bbits(h1v) << 16));
        ast(prow + (LOOF >> 1) + d,
            (unsigned int)bbits(blo(v0, h0)) | ((unsigned int)bbits(blo(v1, h1v)) << 16));
      }
      cnt_add(wcnt + leaf);     // win(brow) published — drain is stores-only now

      // ---- NOW issue register A-prefetch (overlaps h-MFMA + win-bar wait) ----
      const __hip_bfloat16* Ar = S0 + (size_t)(m0 + wv * 16 + lm) * SLOTW;
      short8 pva[16], pua[16];
      #pragma unroll
      for (int c = 0; c < 16; ++c) {
        pva[c] = *(const short8*)(Ar + (c + 2) * 32 + lk);
        pua[c] = *(const short8*)(Ar + LOOF + (c + 2) * 32 + lk);
      }
      floatx4 a0 = {0.f, 0.f, 0.f, 0.f}, a1 = a0;
      #pragma unroll
      for (int c = 0; c < 16; ++c) {
        int col = (c + 2) * 32 + lk;
        short8 vb0 = *(const short8*)(W0h + col);
        short8 vb1 = *(const short8*)(W1h + col);
        short8 ub0 = *(const short8*)(W0l + col);
        short8 ub1 = *(const short8*)(W1l + col);
        a0 = __builtin_amdgcn_mfma_f32_16x16x32_bf16(pva[c], vb0, a0, 0, 0, 0);
        a1 = __builtin_amdgcn_mfma_f32_16x16x32_bf16(pva[c], vb1, a1, 0, 0, 0);
        a0 = __builtin_amdgcn_mfma_f32_16x16x32_bf16(pva[c], ub0, a0, 0, 0, 0);
        a1 = __builtin_amdgcn_mfma_f32_16x16x32_bf16(pva[c], ub1, a1, 0, 0, 0);
        a0 = __builtin_amdgcn_mfma_f32_16x16x32_bf16(pua[c], vb0, a0, 0, 0, 0);
        a1 = __builtin_amdgcn_mfma_f32_16x16x32_bf16(pua[c], vb1, a1, 0, 0, 0);
      }
      waitcnt8(wcnt, 8 * (t + 1));          // all wins of this half available
      gemm3<KW1P>(tid, S1, m0, smWh, smWl, 0, 2, a0, a1);
      store_gsm(tid, Gsm, a0, a1);
      __syncthreads();

      // ---- epilogue: each thread 2 adjacent h-cols of one m-row ----
      {
        int ml = tid >> 2, ppi = tid & 3;
        float v[2];
        #pragma unroll
        for (int j = 0; j < 2; ++j) {
          int nl = ppi * 8 + j * 4;
          float gi = Gsm[(nl + 0) * 65 + ml] + bia[nl + 0];
          float gf = Gsm[(nl + 1) * 65 + ml] + bia[nl + 1];
          float gg = Gsm[(nl + 2) * 65 + ml] + bia[nl + 2];
          float go = Gsm[(nl + 3) * 65 + ml] + bia[nl + 3];
          float ig = 1.f / (1.f + expf(-gi));
          float fg = 1.f / (1.f + expf(-gf));
          float gt = tanhf(gg);
          float og = 1.f / (1.f + expf(-go));
          float cn = fg * creg[j] + ig * gt;
          v[j] = og * tanhf(cn);
          creg[j] = cn;
        }
        __hip_bfloat16 h0 = bhi(v[0]), h1v = bhi(v[1]);
        unsigned int* prow = (unsigned int*)(S1 + (size_t)(m0 + ml) * SLOTW);
        int dw = 32 + nt1 * 4 + ppi;       // hi dword of cols {64+nt1*8+2p, +1}
        ast(prow + dw, (unsigned int)bbits(h0) | ((unsigned int)bbits(h1v) << 16));
        ast(prow + (LOOF >> 1) + dw,
            (unsigned int)bbits(blo(v[0], h0)) | ((unsigned int)bbits(blo(v[1], h1v)) << 16));
        if (t == T - 1) {
          int hg = nt1 * 8 + 2 * ppi;
          h1f[(m0 + ml) * H + hg]     = v[0];  c1f[(m0 + ml) * H + hg]     = creg[0];
          h1f[(m0 + ml) * H + hg + 1] = v[1];  c1f[(m0 + ml) * H + hg + 1] = creg[1];
        }
      }
      cnt_add(hcnt + leaf);                 // h1 slice published (drains win+h)
    }
  } else {
    // ========== G2: lstm2 ==========
    const int g = gid - 128;
    const int nt2 = g >> 1, mh = g & 1;
    const int n0 = nt2 * 32, m0 = mh * 64;
    const int leaf = (nt2 & 7) * 32;
    int* hcnt = ctl + mh * 256;
    int* h2g  = ctl + 1024 + mh * 256;
    __hip_bfloat16* smWh = (__hip_bfloat16*)(sm + O_WH2);
    __hip_bfloat16* smWl = (__hip_bfloat16*)(sm + O_WL2);
    float* Gsm = (float*)(sm + O_GS2);
    float* bia = (float*)(sm + O_BI2);

    for (int i = tid; i < 32 * 136; i += 256) {
      int r = i / 136, c8 = (i - r * 136) * 8;
      *(short8*)(smWh + r * KW2P + c8) = *(const short8*)(wc2  + (size_t)(n0 + r) * K2 + c8);
      *(short8*)(smWl + r * KW2P + c8) = *(const short8*)(wc2l + (size_t)(n0 + r) * K2 + c8);
    }
    if (tid < 32) bia[tid] = bi2[n0 + tid];
    __syncthreads();

    float creg[2];
    {
      int ml = tid >> 2, ppi = tid & 3;
      creg[0] = c2init[(m0 + ml) * H + nt2 * 8 + 2 * ppi + 0];
      creg[1] = c2init[(m0 + ml) * H + nt2 * 8 + 2 * ppi + 1];
    }

    const __hip_bfloat16* W0h = smWh + lm * KW2P;
    const __hip_bfloat16* W1h = smWh + (16 + lm) * KW2P;
    const __hip_bfloat16* W0l = smWl + lm * KW2P;
    const __hip_bfloat16* W1l = smWl + (16 + lm) * KW2P;

    for (int t = 0; t < T; ++t) {
      __hip_bfloat16* S1 = fxHL + (size_t)(t + 1) * SLOTE;
      __hip_bfloat16* S2 = fxHL + (size_t)(t + 2) * SLOTE;
      const __hip_bfloat16* Ar = S1 + (size_t)(m0 + wv * 16 + lm) * SLOTW;

      // own-half h2_{t-1} complete in S1 -> prefetch h2-part A (hi only)
      waitcnt8(h2g, 8 * t);
      short8 pv2[16];
      #pragma unroll
      for (int c = 0; c < 16; ++c)
        pv2[c] = *(const short8*)(Ar + (K1C + c) * 32 + lk);
      floatx4 a0 = {0.f, 0.f, 0.f, 0.f}, a1 = a0;
      #pragma unroll
      for (int c = 0; c < 16; ++c) {
        int col = (K1C + c) * 32 + lk;
        short8 vb0 = *(const short8*)(W0h + col);
        short8 vb1 = *(const short8*)(W1h + col);
        short8 ub0 = *(const short8*)(W0l + col);
        short8 ub1 = *(const short8*)(W1l + col);
        a0 = __builtin_amdgcn_mfma_f32_16x16x32_bf16(pv2[c], vb0, a0, 0, 0, 0);
        a1 = __builtin_amdgcn_mfma_f32_16x16x32_bf16(pv2[c], vb1, a1, 0, 0, 0);
        a0 = __builtin_amdgcn_mfma_f32_16x16x32_bf16(pv2[c], ub0, a0, 0, 0, 0);
        a1 = __builtin_amdgcn_mfma_f32_16x16x32_bf16(pv2[c], ub1, a1, 0, 0, 0);
      }
      // win_t and h1_t in S1: hcnt covers both (win stores drained before add)
      waitcnt8(hcnt, 8 * (t + 1));
      short8 qv[18], qu[18];
      #pragma unroll
      for (int c = 0; c < 18; ++c) {
        qv[c] = *(const short8*)(Ar + c * 32 + lk);
        qu[c] = *(const short8*)(Ar + LOOF + c * 32 + lk);
      }
      #pragma unroll
      for (int c = 0; c < 18; ++c) {
        int col = c * 32 + lk;
        short8 vb0 = *(const short8*)(W0h + col);
        short8 vb1 = *(const short8*)(W1h + col);
        short8 ub0 = *(const short8*)(W0l + col);
        short8 ub1 = *(const short8*)(W1l + col);
        a0 = __builtin_amdgcn_mfma_f32_16x16x32_bf16(qv[c], vb0, a0, 0, 0, 0);
        a1 = __builtin_amdgcn_mfma_f32_16x16x32_bf16(qv[c], vb1, a1, 0, 0, 0);
        a0 = __builtin_amdgcn_mfma_f32_16x16x32_bf16(qv[c], ub0, a0, 0, 0, 0);
        a1 = __builtin_amdgcn_mfma_f32_16x16x32_bf16(qv[c], ub1, a1, 0, 0, 0);
        a0 = __builtin_amdgcn_mfma_f32_16x16x32_bf16(qu[c], vb0, a0, 0, 0, 0);
        a1 = __builtin_amdgcn_mfma_f32_16x16x32_bf16(qu[c], vb1, a1, 0, 0, 0);
      }
      store_gsm(tid, Gsm, a0, a1);
      __syncthreads();

      {
        int ml = tid >> 2, ppi = tid & 3;
        float v[2];
        #pragma unroll
        for (int j = 0; j < 2; ++j) {
          int nl = ppi * 8 + j * 4;
          float gi = Gsm[(nl + 0) * 65 + ml] + bia[nl + 0];
          float gf = Gsm[(nl + 1) * 65 + ml] + bia[nl + 1];
          float gg = Gsm[(nl + 2) * 65 + ml] + bia[nl + 2];
          float go = Gsm[(nl + 3) * 65 + ml] + bia[nl + 3];
          float ig = 1.f / (1.f + expf(-gi));
          float fg = 1.f / (1.f + expf(-gf));
          float gt = tanhf(gg);
          float og = 1.f / (1.f + expf(-go));
          float cn = fg * creg[j] + ig * gt;
          v[j] = og * tanhf(cn);
          creg[j] = cn;
        }
        __hip_bfloat16 h0 = bhi(v[0]), h1v = bhi(v[1]);
        unsigned int* prow = (unsigned int*)(S2 + (size_t)(m0 + ml) * SLOTW);
        int dw = 288 + nt2 * 4 + ppi;      // hi dword of cols {576+nt2*8+2p, +1}
        ast(prow + dw, (unsigned int)bbits(h0) | ((unsigned int)bbits(h1v) << 16));
        if (t == T - 1) {
          int hg = nt2 * 8 + 2 * ppi;
          h2f[(m0 + ml) * H + hg]     = v[0];  c2f[(m0 + ml) * H + hg]     = creg[0];
          h2f[(m0 + ml) * H + hg + 1] = v[1];  c2f[(m0 + ml) * H + hg + 1] = creg[1];
        }
      }
      cnt_add(h2g + leaf);                  // h2 slice published
    }
  }
}

// ---------------- final GEMM: out[BT x 121] = h2 @ W2^T + b2 ----------------
__global__ __launch_bounds__(256) void k_out(
    const __hip_bfloat16* __restrict__ fxHL, const __hip_bfloat16* __restrict__ w2b,
    const float* __restrict__ b2, float* __restrict__ dout)
{
  int bid = blockIdx.x, tid = threadIdx.x;
  int mblk = bid >> 1, nblk = bid & 1;
  int wv = tid >> 6, lane = tid & 63;
  int lm = lane & 15, lk = (lane >> 4) << 3;
  int m0 = mblk * 128 + wv * 32;
  int n0 = nblk * 64;
  int r0 = m0 + lm, r1 = m0 + 16 + lm;
  const __hip_bfloat16* a0p = fxHL + (size_t)((r0 & 255) + 2) * SLOTE + (r0 >> 8) * SLOTW + 576;
  const __hip_bfloat16* a1p = fxHL + (size_t)((r1 & 255) + 2) * SLOTE + (r1 >> 8) * SLOTW + 576;
  floatx4 zz = {0.f, 0.f, 0.f, 0.f};
  floatx4 acc[2][4];
  #pragma unroll
  for (int mt = 0; mt < 2; ++mt)
    #pragma unroll
    for (int nt = 0; nt < 4; ++nt) acc[mt][nt] = zz;
  #pragma unroll
  for (int c = 0; c < 16; ++c) {
    int col = c * 32 + lk;
    short8 va0 = *(const short8*)(a0p + col);
    short8 va1 = *(const short8*)(a1p + col);
    short8 vb[4];
    #pragma unroll
    for (int nt = 0; nt < 4; ++nt)
      vb[nt] = *(const short8*)(w2b + (size_t)(n0 + nt * 16 + lm) * 512 + col);
    #pragma unroll
    for (int nt = 0; nt < 4; ++nt) {
      acc[0][nt] = __builtin_amdgcn_mfma_f32_16x16x32_bf16(va0, vb[nt], acc[0][nt], 0, 0, 0);
      acc[1][nt] = __builtin_amdgcn_mfma_f32_16x16x32_bf16(va1, vb[nt], acc[1][nt], 0, 0, 0);
    }
  }
  int rr = (lane >> 4) << 2;
  #pragma unroll
  for (int mt = 0; mt < 2; ++mt)
    #pragma unroll
    for (int nt = 0; nt < 4; ++nt)
      #pragma unroll
      for (int r = 0; r < 4; ++r) {
        int m = m0 + mt * 16 + rr + r;
        int n = n0 + nt * 16 + lm;
        if (n < OUTW) dout[(size_t)m * OUTW + n] = acc[mt][nt][r] + b2[n];
      }
}

// ---------------- host ----------------
extern "C" void kernel_launch(void* const* d_in, const int* in_sizes, int n_in,
                              void* d_out, int out_size, void* d_ws, size_t ws_size,
                              hipStream_t stream)
{
  (void)in_sizes; (void)n_in; (void)out_size; (void)ws_size;
  const float* x    = (const float*)d_in[0];
  const float* sent = (const float*)d_in[1];
  const float* h1h  = (const float*)d_in[2];
  const float* h1c  = (const float*)d_in[3];
  const float* h2h  = (const float*)d_in[4];
  const float* h2c  = (const float*)d_in[5];
  const float* Wihc = (const float*)d_in[6];
  const float* Whhc = (const float*)d_in[7];
  const float* bc   = (const float*)d_in[8];
  const float* Wihl = (const float*)d_in[9];
  const float* Whhl = (const float*)d_in[10];
  const float* bl   = (const float*)d_in[11];
  const float* W1   = (const float*)d_in[12];
  const float* b1   = (const float*)d_in[13];
  const float* W2   = (const float*)d_in[14];
  const float* b2   = (const float*)d_in[15];

  float* out = (float*)d_out;
  float* h1f = out + (size_t)B * T * OUTW;
  float* c1f = h1f + (size_t)B * H;
  float* h2f = c1f + (size_t)B * H;
  float* c2f = h2f + (size_t)B * H;

  char* p = (char*)d_ws;
  auto carve = [&](size_t bytes) { char* r = p; p += (bytes + 255) & ~(size_t)255; return r; };
  __hip_bfloat16* fxHL = (__hip_bfloat16*)carve((size_t)NSLOT * SLOTE * 2);
  __hip_bfloat16* wc1  = (__hip_bfloat16*)carve((size_t)NG * K1 * 2);
  __hip_bfloat16* wc1l = (__hip_bfloat16*)carve((size_t)NG * K1 * 2);
  __hip_bfloat16* wc2  = (__hip_bfloat16*)carve((size_t)NG * K2 * 2);
  __hip_bfloat16* wc2l = (__hip_bfloat16*)carve((size_t)NG * K2 * 2);
  __hip_bfloat16* w2b  = (__hip_bfloat16*)carve((size_t)128 * 512 * 2);
  float* bi1 = (float*)carve((size_t)NG * 4);
  float* bi2 = (float*)carve((size_t)NG * 4);
  int*   ctl = (int*)carve((size_t)2048 * 4);

  static bool attr_set = false;
  if (!attr_set) {
    (void)hipFuncSetAttribute((const void*)k_persist,
                              hipFuncAttributeMaxDynamicSharedMemorySize, LDS_SZ);
    attr_set = true;
  }

  k_pre<<<14232, 256, 0, stream>>>(x, h1h, h2h, Wihc, Whhc, bc, Wihl, Whhl, bl, W2,
                                   fxHL, wc1, wc1l, wc2, wc2l, w2b, bi1, bi2, ctl);
  k_persist<<<256, 256, LDS_SZ, stream>>>(fxHL, wc1, wc1l, wc2, wc2l, bi1, bi2,
                                          h1c, h2c, x, sent, W1, b1, ctl,
                                          h1f, c1f, h2f, c2f);
  k_out<<<512, 256, 0, stream>>>(fxHL, w2b, b2, out);
}

// Round 4
// 2692.156 us; speedup vs baseline: 1.1684x; 1.1684x over previous
//
#include <hip/hip_runtime.h>
#include <hip/hip_bf16.h>
#include <math.h>

typedef __attribute__((ext_vector_type(8))) short short8;
typedef __attribute__((ext_vector_type(4))) float floatx4;

#define DEVFN static __device__ __forceinline__

constexpr int B = 128, T = 256, H = 512;
constexpr int OUTW = 121;
// fxHL slot row layout (per batch row, per time slot), elems:
//   hi: [x(3) win(60) pad(1) h1(512) h2(512)] = 1088
//   lo: cols 0..575 only (x,win,h1)           = 576
constexpr int SLOTW = 1664;              // row stride in elems (hi 1088 + lo 576)
constexpr int LOOF  = 1088;              // lo region offset within row
constexpr int SLOTE = B * SLOTW;         // elems per time slot
constexpr int NSLOT = T + 2;
constexpr int NG  = 2048;                // 4*H gate rows (interleaved n' = hcol*4+gate)
constexpr int K1  = 576,  K1C = 18;
constexpr int K2  = 1088, K2C = 34;
constexpr int KW1P = 584, KW2P = 1096;   // LDS weight row pads

// ---- LDS offsets (bytes) ----
// G1 path. NOTE: hs/pp alias the Gsm region — window phase and GEMM phase are
// temporally disjoint (separated by barriers).
constexpr int O_WH1 = 0;                 // 32*584*2 = 37376
constexpr int O_WL1 = 37376;             // -> 74752
constexpr int O_W1S = 74752;             // 30*520*4 = 62400 -> 137152
constexpr int O_GSM = 137152;            // 32*65*4 = 8320 -> 145472
constexpr int O_HS  = 137152;            // 528*4 = 2112 (alias in Gsm)
constexpr int O_PP  = 139264;            // 240*4 = 960 (alias in Gsm)
constexpr int O_IPL = 145472;            // 30*4
constexpr int O_KL  = 145592;            // 10*4
constexpr int O_PHL = 145632;            // 64*4
constexpr int O_WAC = 145888;            // 240*4
constexpr int O_KPR = 146848;            // 10*4
constexpr int O_B1S = 146888;            // 30*4
constexpr int O_BIA = 147008;            // 32*4 -> 147136
constexpr int O_SENT = 147136;           // 64*60 fp32 = 15360 -> 162496
// G2 path:
constexpr int O_WH2 = 0;                 // 32*1096*2 = 70144
constexpr int O_WL2 = 70144;             // -> 140288
constexpr int O_GS2 = 140288;            // 8320 -> 148608
constexpr int O_BI2 = 148608;            // 128 -> 148736
constexpr int LDS_SZ = 162496;

DEVFN __hip_bfloat16 bhi(float v) { return __float2bfloat16(v); }
DEVFN __hip_bfloat16 blo(float v, __hip_bfloat16 h) { return __float2bfloat16(v - __bfloat162float(h)); }
DEVFN float bf2f(__hip_bfloat16 h) { return __bfloat162float(h); }
DEVFN unsigned short bbits(__hip_bfloat16 h) { union { __hip_bfloat16 h; unsigned short u; } c; c.h = h; return c.u; }
DEVFN unsigned int pack2(float a, float b) {
  return (unsigned int)bbits(bhi(a)) | ((unsigned int)bbits(bhi(b)) << 16);
}
DEVFN void ast(unsigned int* p, unsigned int v) {
  __hip_atomic_store(p, v, __ATOMIC_RELAXED, __HIP_MEMORY_SCOPE_AGENT);
}
DEVFN int ald(int* p) {
  return __hip_atomic_load(p, __ATOMIC_RELAXED, __HIP_MEMORY_SCOPE_AGENT);
}

// ---- 8-leaf tree-counter barriers ----
// Each barrier group = 64 blocks. Producers add to leaf (nt&7); each leaf on
// its own 128B line -> 8 serialized RMWs/line instead of 64. Consumers: 8
// threads each poll one leaf for >= 8*step.
DEVFN void waitcnt8(int* base, int target) {
  if (threadIdx.x < 8) {
    int* p = base + threadIdx.x * 32;
    int g = 0;
    while (ald(p) < target && g < (1 << 24)) { ++g; __builtin_amdgcn_s_sleep(1); }
  }
  asm volatile("" ::: "memory");
  __syncthreads();
}
// Producer: drain own stores (all waves), then one atomic increment to leaf.
DEVFN void cnt_add(int* leaf) {
  asm volatile("s_waitcnt vmcnt(0)" ::: "memory");
  __syncthreads();
  if (threadIdx.x == 0)
    (void)__hip_atomic_fetch_add(leaf, 1, __ATOMIC_RELAXED, __HIP_MEMORY_SCOPE_AGENT);
}

// ---------------- precompute ----------------
__global__ __launch_bounds__(256) void k_pre(
    const float* __restrict__ x, const float* __restrict__ h1h, const float* __restrict__ h2h,
    const float* __restrict__ Wihc, const float* __restrict__ Whhc, const float* __restrict__ bc,
    const float* __restrict__ Wihl, const float* __restrict__ Whhl, const float* __restrict__ bl,
    const float* __restrict__ W2,
    __hip_bfloat16* __restrict__ fxHL,
    __hip_bfloat16* __restrict__ wc1, __hip_bfloat16* __restrict__ wc1l,
    __hip_bfloat16* __restrict__ wc2, __hip_bfloat16* __restrict__ wc2l,
    __hip_bfloat16* __restrict__ w2b, float* __restrict__ bi1, float* __restrict__ bi2,
    int* __restrict__ ctl)
{
  int idx = blockIdx.x * 256 + threadIdx.x;
  const int nwc1 = NG * K1, nwc2 = NG * K2, nw2b = 128 * 512, nbi = 2 * NG;
  const int nfh = B * H, nxj = T * B, nctl = 2048;
  if (idx < nwc1) {
    int n = idx / K1, col = idx - n * K1;
    int src = (n & 3) * H + (n >> 2);
    float v = (col < 63) ? Wihc[src * 63 + col]
            : (col == 63 ? 0.f : Whhc[src * 512 + (col - 64)]);
    __hip_bfloat16 h = bhi(v);
    wc1[n * K1 + col] = h; wc1l[n * K1 + col] = blo(v, h);
    return;
  }
  idx -= nwc1;
  if (idx < nwc2) {
    int n = idx / K2, col = idx - n * K2;
    int src = (n & 3) * H + (n >> 2);
    float v;
    if (col < 63)       v = Wihl[src * 575 + col];
    else if (col == 63) v = 0.f;
    else if (col < 576) v = Wihl[src * 575 + (col - 1)];
    else                v = Whhl[src * 512 + (col - 576)];
    __hip_bfloat16 h = bhi(v);
    wc2[n * K2 + col] = h; wc2l[n * K2 + col] = blo(v, h);
    return;
  }
  idx -= nwc2;
  if (idx < nw2b) {
    int n = idx >> 9, col = idx & 511;
    w2b[idx] = bhi(n < OUTW ? W2[n * 512 + col] : 0.f);
    return;
  }
  idx -= nw2b;
  if (idx < nbi) {
    int n = idx & (NG - 1);
    int src = (n & 3) * H + (n >> 2);
    if (idx < NG) bi1[n] = bc[src]; else bi2[n] = bl[src];
    return;
  }
  idx -= nbi;
  if (idx < nfh) {  // slot0 h1 init (hi+lo)
    int b = idx >> 9, j = idx & 511;
    float v = h1h[idx];
    __hip_bfloat16 h = bhi(v);
    fxHL[b * SLOTW + 64 + j] = h;
    fxHL[b * SLOTW + LOOF + 64 + j] = blo(v, h);
    return;
  }
  idx -= nfh;
  if (idx < nfh) {  // slot1 h2 init (hi only)
    int b = idx >> 9, j = idx & 511;
    fxHL[(size_t)SLOTE + b * SLOTW + 576 + j] = bhi(h2h[idx]);
    return;
  }
  idx -= nfh;
  if (idx < nxj) {  // x cols {0,1} hi + lo zeros for slot t+1
    int t = idx >> 7, b = idx & 127;
    float x0 = x[(b * T + t) * 3 + 0], x1 = x[(b * T + t) * 3 + 1];
    unsigned int* ph = (unsigned int*)(fxHL + (size_t)(t + 1) * SLOTE + b * SLOTW);
    ph[0] = pack2(x0, x1);
    unsigned int* pl = (unsigned int*)(fxHL + (size_t)(t + 1) * SLOTE + b * SLOTW + LOOF);
    pl[0] = 0u;
    return;
  }
  idx -= nxj;
  if (idx < nctl) ctl[idx] = 0;
}

// ---------------- MFMA helper (A rows from global, W in LDS) ----------------
template <int KWP>
DEVFN void gemm3(int tid, const __hip_bfloat16* __restrict__ Aslot, int m0,
                 const __hip_bfloat16* __restrict__ Wh, const __hip_bfloat16* __restrict__ Wl,
                 int cbeg, int cend, floatx4& a0, floatx4& a1)
{
  const int lane = tid & 63, wv = tid >> 6;
  const int lm = lane & 15, lk = (lane >> 4) << 3;
  const __hip_bfloat16* Ar = Aslot + (size_t)(m0 + wv * 16 + lm) * SLOTW;
  const __hip_bfloat16* W0h = Wh + lm * KWP;
  const __hip_bfloat16* W1h = Wh + (16 + lm) * KWP;
  const __hip_bfloat16* W0l = Wl + lm * KWP;
  const __hip_bfloat16* W1l = Wl + (16 + lm) * KWP;
  #pragma unroll 4
  for (int c = cbeg; c < cend; ++c) {
    int col = c * 32 + lk;
    short8 va  = *(const short8*)(Ar + col);
    short8 ua  = *(const short8*)(Ar + LOOF + col);
    short8 vb0 = *(const short8*)(W0h + col);
    short8 vb1 = *(const short8*)(W1h + col);
    short8 ub0 = *(const short8*)(W0l + col);
    short8 ub1 = *(const short8*)(W1l + col);
    a0 = __builtin_amdgcn_mfma_f32_16x16x32_bf16(va, vb0, a0, 0, 0, 0);
    a1 = __builtin_amdgcn_mfma_f32_16x16x32_bf16(va, vb1, a1, 0, 0, 0);
    a0 = __builtin_amdgcn_mfma_f32_16x16x32_bf16(va, ub0, a0, 0, 0, 0);
    a1 = __builtin_amdgcn_mfma_f32_16x16x32_bf16(va, ub1, a1, 0, 0, 0);
    a0 = __builtin_amdgcn_mfma_f32_16x16x32_bf16(ua, vb0, a0, 0, 0, 0);
    a1 = __builtin_amdgcn_mfma_f32_16x16x32_bf16(ua, vb1, a1, 0, 0, 0);
  }
}

DEVFN void store_gsm(int tid, float* Gsm, floatx4 a0, floatx4 a1) {
  const int lane = tid & 63, wv = tid >> 6;
  const int lm = lane & 15, rr = (lane >> 4) << 2;
  #pragma unroll
  for (int r = 0; r < 4; ++r) {
    Gsm[lm * 65 + wv * 16 + rr + r]        = a0[r];
    Gsm[(16 + lm) * 65 + wv * 16 + rr + r] = a1[r];
  }
}

// ---------------- persistent fused kernel ----------------
__global__ __launch_bounds__(256, 1) void k_persist(
    __hip_bfloat16* __restrict__ fxHL,
    const __hip_bfloat16* __restrict__ wc1, const __hip_bfloat16* __restrict__ wc1l,
    const __hip_bfloat16* __restrict__ wc2, const __hip_bfloat16* __restrict__ wc2l,
    const float* __restrict__ bi1, const float* __restrict__ bi2,
    const float* __restrict__ c1init, const float* __restrict__ c2init,
    const float* __restrict__ xin, const float* __restrict__ sent,
    const float* __restrict__ W1, const float* __restrict__ b1,
    int* __restrict__ ctl,
    float* __restrict__ h1f, float* __restrict__ c1f,
    float* __restrict__ h2f, float* __restrict__ c2f)
{
  extern __shared__ char sm[];
  const int gid = blockIdx.x, tid = threadIdx.x;
  const int lane = tid & 63, wv = tid >> 6;
  const int lm = lane & 15, lk = (lane >> 4) << 3;

  if (gid < 128) {
    // ========== G1: window + lstm1 ==========
    const int nt1 = gid >> 1, mh = gid & 1;
    const int n0 = nt1 * 32, m0 = mh * 64;
    const int brow = mh * 64 + nt1;
    const int leaf = (nt1 & 7) * 32;
    int* hcnt = ctl + mh * 256;            // h1 step completion tree (8 leaves)
    int* wcnt = ctl + 512 + mh * 256;      // win publication tree
    __hip_bfloat16* smWh = (__hip_bfloat16*)(sm + O_WH1);
    __hip_bfloat16* smWl = (__hip_bfloat16*)(sm + O_WL1);
    float* smW1 = (float*)(sm + O_W1S);
    float* Gsm  = (float*)(sm + O_GSM);
    float* hs   = (float*)(sm + O_HS);   // aliases Gsm region (window phase only)
    float* pp   = (float*)(sm + O_PP);   // aliases Gsm region (window phase only)
    float* ipl  = (float*)(sm + O_IPL);
    float* kl   = (float*)(sm + O_KL);
    float* phl  = (float*)(sm + O_PHL);
    float* wac  = (float*)(sm + O_WAC);
    float* kpr  = (float*)(sm + O_KPR);
    float* b1s  = (float*)(sm + O_B1S);
    float* bia  = (float*)(sm + O_BIA);
    float* ssent = (float*)(sm + O_SENT);

    for (int i = tid; i < 32 * 72; i += 256) {
      int r = i / 72, c8 = (i - r * 72) * 8;
      *(short8*)(smWh + r * KW1P + c8) = *(const short8*)(wc1  + (size_t)(n0 + r) * K1 + c8);
      *(short8*)(smWl + r * KW1P + c8) = *(const short8*)(wc1l + (size_t)(n0 + r) * K1 + c8);
    }
    for (int i = tid; i < 30 * 512; i += 256) {
      int j = i >> 9, c = i & 511;
      smW1[j * 520 + (c >> 6) * 65 + (c & 63)] = W1[i];
    }
    for (int i = tid; i < 64 * 60; i += 256)
      ssent[i] = sent[(size_t)brow * 64 * 60 + i];   // fp32 — bf16 here fails c1f (R7)
    if (tid < 30) b1s[tid] = b1[tid];
    if (tid < 10) kpr[tid] = 0.f;
    if (tid < 32) bia[tid] = bi1[n0 + tid];
    __syncthreads();

    float creg[2];
    {
      int ml = tid >> 2, ppi = tid & 3;
      creg[0] = c1init[(m0 + ml) * H + nt1 * 8 + 2 * ppi + 0];
      creg[1] = c1init[(m0 + ml) * H + nt1 * 8 + 2 * ppi + 1];
    }

    const __hip_bfloat16* W0h = smWh + lm * KW1P;
    const __hip_bfloat16* W1h = smWh + (16 + lm) * KW1P;
    const __hip_bfloat16* W0l = smWl + lm * KW1P;
    const __hip_bfloat16* W1l = smWl + (16 + lm) * KW1P;

    for (int t = 0; t < T; ++t) {
      __hip_bfloat16* S1 = fxHL + (size_t)(t + 1) * SLOTE;
      __hip_bfloat16* S0 = fxHL + (size_t)t * SLOTE;

      waitcnt8(hcnt, 8 * t);   // all same-half h1_{t-1} published

      // ---- own h-row loads + x scalar, then register A-prefetch ----
      // PREFETCH PLACEMENT IS LOAD-BEARING (R3 lesson): issuing pva/pua HERE,
      // with the whole window phase between issue and consumption, keeps them
      // live in VGPRs (~112) and their latency hidden. Issuing them next to
      // the consuming MFMA loop makes the compiler sink the loads into the
      // loop (VGPR 48) and serialize load->mfma: +300 us total.
      const __hip_bfloat16* wrow = S0 + (size_t)brow * SLOTW;
      __hip_bfloat16 a0h = wrow[64 + tid];
      __hip_bfloat16 a0l = wrow[LOOF + 64 + tid];
      __hip_bfloat16 a1h = wrow[64 + 256 + tid];
      __hip_bfloat16 a1l = wrow[LOOF + 64 + 256 + tid];
      float x2v = xin[(brow * T + t) * 3 + 2];
      const __hip_bfloat16* Ar = S0 + (size_t)(m0 + wv * 16 + lm) * SLOTW;
      short8 pva[16], pua[16];
      #pragma unroll
      for (int c = 0; c < 16; ++c) {
        pva[c] = *(const short8*)(Ar + (c + 2) * 32 + lk);
        pua[c] = *(const short8*)(Ar + LOOF + (c + 2) * 32 + lk);
      }
      hs[(tid >> 6) * 66 + (tid & 63)] = bf2f(a0h) + bf2f(a0l);
      hs[((tid + 256) >> 6) * 66 + (tid & 63)] = bf2f(a1h) + bf2f(a1l);
      __syncthreads();

      // ---- window compute (LDS only; A-prefetch in flight) ----
      if (tid < 240) {
        int j = tid >> 3, p = tid & 7;
        const float* wp = smW1 + j * 520 + p * 65;
        const float* hv = hs + p * 66;
        float s = 0.f;
        #pragma unroll 8
        for (int k = 0; k < 64; ++k) s += hv[k] * wp[k];
        pp[tid] = s;
      }
      __syncthreads();
      if (tid < 30) {       // merged ip-exp + kappa stage (wave 0 only)
        float s = b1s[tid];
        #pragma unroll
        for (int p = 0; p < 8; ++p) s += pp[tid * 8 + p];
        float e = expf(s);
        ipl[tid] = e;
        if (tid >= 20) {
          float kap = e - kpr[tid - 20];
          kpr[tid - 20] = kap; kl[tid - 20] = kap;
        }
      }
      // wave-local hand-off (both stages wave 0): LDS writes complete, no
      // block barrier needed; "memory" clobber pins the ds op order.
      asm volatile("s_waitcnt lgkmcnt(0)" ::: "memory");
      if (tid < 64) {
        float u = (float)(tid + 1);
        float acc = 0.f;
        #pragma unroll
        for (int k = 0; k < 10; ++k) {
          float d = kl[k] - u;
          acc += ipl[k] * expf(-ipl[10 + k] * d * d);
        }
        phl[tid] = acc;
      }
      __syncthreads();
      if (tid < 240) {
        int c = tid >> 2, p = tid & 3;
        float acc = 0.f;
        #pragma unroll
        for (int s0 = 0; s0 < 16; ++s0)
          acc += phl[p * 16 + s0] * ssent[(p * 16 + s0) * 60 + c];
        wac[tid] = acc;
      }
      __syncthreads();
      if (tid < 31) {  // publish win; winv reduction folded in (8 adds/thread)
        int d = 1 + tid;
        int c0 = 2 * d, c1 = 2 * d + 1;
        float v0, v1;
        if (c0 == 2) v0 = x2v;
        else { int j = (c0 - 3) * 4; v0 = wac[j] + wac[j + 1] + wac[j + 2] + wac[j + 3]; }
        if (c1 == 63) v1 = 0.f;
        else { int j = (c1 - 3) * 4; v1 = wac[j] + wac[j + 1] + wac[j + 2] + wac[j + 3]; }
        __hip_bfloat16 h0 = bhi(v0), h1v = bhi(v1);
        unsigned int* prow = (unsigned int*)(S1 + (size_t)brow * SLOTW);
        ast(prow + d, (unsigned int)bbits(h0) | ((unsigned int)bbits(h1v) << 16));
        ast(prow + (LOOF >> 1) + d,
            (unsigned int)bbits(blo(v0, h0)) | ((unsigned int)bbits(blo(v1, h1v)) << 16));
      }
      cnt_add(wcnt + leaf);     // win(brow) published

      // ---- h1-part MFMA from prefetched registers (no global loads) ----
      floatx4 a0 = {0.f, 0.f, 0.f, 0.f}, a1 = a0;
      #pragma unroll
      for (int c = 0; c < 16; ++c) {
        int col = (c + 2) * 32 + lk;
        short8 vb0 = *(const short8*)(W0h + col);
        short8 vb1 = *(const short8*)(W1h + col);
        short8 ub0 = *(const short8*)(W0l + col);
        short8 ub1 = *(const short8*)(W1l + col);
        a0 = __builtin_amdgcn_mfma_f32_16x16x32_bf16(pva[c], vb0, a0, 0, 0, 0);
        a1 = __builtin_amdgcn_mfma_f32_16x16x32_bf16(pva[c], vb1, a1, 0, 0, 0);
        a0 = __builtin_amdgcn_mfma_f32_16x16x32_bf16(pva[c], ub0, a0, 0, 0, 0);
        a1 = __builtin_amdgcn_mfma_f32_16x16x32_bf16(pva[c], ub1, a1, 0, 0, 0);
        a0 = __builtin_amdgcn_mfma_f32_16x16x32_bf16(pua[c], vb0, a0, 0, 0, 0);
        a1 = __builtin_amdgcn_mfma_f32_16x16x32_bf16(pua[c], vb1, a1, 0, 0, 0);
      }
      waitcnt8(wcnt, 8 * (t + 1));          // all wins of this half available
      gemm3<KW1P>(tid, S1, m0, smWh, smWl, 0, 2, a0, a1);
      store_gsm(tid, Gsm, a0, a1);
      __syncthreads();

      // ---- epilogue: each thread 2 adjacent h-cols of one m-row ----
      {
        int ml = tid >> 2, ppi = tid & 3;
        float v[2];
        #pragma unroll
        for (int j = 0; j < 2; ++j) {
          int nl = ppi * 8 + j * 4;
          float gi = Gsm[(nl + 0) * 65 + ml] + bia[nl + 0];
          float gf = Gsm[(nl + 1) * 65 + ml] + bia[nl + 1];
          float gg = Gsm[(nl + 2) * 65 + ml] + bia[nl + 2];
          float go = Gsm[(nl + 3) * 65 + ml] + bia[nl + 3];
          float ig = 1.f / (1.f + expf(-gi));
          float fg = 1.f / (1.f + expf(-gf));
          float gt = tanhf(gg);
          float og = 1.f / (1.f + expf(-go));
          float cn = fg * creg[j] + ig * gt;
          v[j] = og * tanhf(cn);
          creg[j] = cn;
        }
        __hip_bfloat16 h0 = bhi(v[0]), h1v = bhi(v[1]);
        unsigned int* prow = (unsigned int*)(S1 + (size_t)(m0 + ml) * SLOTW);
        int dw = 32 + nt1 * 4 + ppi;       // hi dword of cols {64+nt1*8+2p, +1}
        ast(prow + dw, (unsigned int)bbits(h0) | ((unsigned int)bbits(h1v) << 16));
        ast(prow + (LOOF >> 1) + dw,
            (unsigned int)bbits(blo(v[0], h0)) | ((unsigned int)bbits(blo(v[1], h1v)) << 16));
        if (t == T - 1) {
          int hg = nt1 * 8 + 2 * ppi;
          h1f[(m0 + ml) * H + hg]     = v[0];  c1f[(m0 + ml) * H + hg]     = creg[0];
          h1f[(m0 + ml) * H + hg + 1] = v[1];  c1f[(m0 + ml) * H + hg + 1] = creg[1];
        }
      }
      cnt_add(hcnt + leaf);                 // h1 slice published (drains win+h)
    }
  } else {
    // ========== G2: lstm2 ==========
    const int g = gid - 128;
    const int nt2 = g >> 1, mh = g & 1;
    const int n0 = nt2 * 32, m0 = mh * 64;
    const int leaf = (nt2 & 7) * 32;
    int* hcnt = ctl + mh * 256;
    int* h2g  = ctl + 1024 + mh * 256;
    __hip_bfloat16* smWh = (__hip_bfloat16*)(sm + O_WH2);
    __hip_bfloat16* smWl = (__hip_bfloat16*)(sm + O_WL2);
    float* Gsm = (float*)(sm + O_GS2);
    float* bia = (float*)(sm + O_BI2);

    for (int i = tid; i < 32 * 136; i += 256) {
      int r = i / 136, c8 = (i - r * 136) * 8;
      *(short8*)(smWh + r * KW2P + c8) = *(const short8*)(wc2  + (size_t)(n0 + r) * K2 + c8);
      *(short8*)(smWl + r * KW2P + c8) = *(const short8*)(wc2l + (size_t)(n0 + r) * K2 + c8);
    }
    if (tid < 32) bia[tid] = bi2[n0 + tid];
    __syncthreads();

    float creg[2];
    {
      int ml = tid >> 2, ppi = tid & 3;
      creg[0] = c2init[(m0 + ml) * H + nt2 * 8 + 2 * ppi + 0];
      creg[1] = c2init[(m0 + ml) * H + nt2 * 8 + 2 * ppi + 1];
    }

    const __hip_bfloat16* W0h = smWh + lm * KW2P;
    const __hip_bfloat16* W1h = smWh + (16 + lm) * KW2P;
    const __hip_bfloat16* W0l = smWl + lm * KW2P;
    const __hip_bfloat16* W1l = smWl + (16 + lm) * KW2P;

    for (int t = 0; t < T; ++t) {
      __hip_bfloat16* S1 = fxHL + (size_t)(t + 1) * SLOTE;
      __hip_bfloat16* S2 = fxHL + (size_t)(t + 2) * SLOTE;
      const __hip_bfloat16* Ar = S1 + (size_t)(m0 + wv * 16 + lm) * SLOTW;

      // own-half h2_{t-1} complete in S1 -> prefetch h2-part A (hi only)
      waitcnt8(h2g, 8 * t);
      short8 pv2[16];
      #pragma unroll
      for (int c = 0; c < 16; ++c)
        pv2[c] = *(const short8*)(Ar + (K1C + c) * 32 + lk);
      floatx4 a0 = {0.f, 0.f, 0.f, 0.f}, a1 = a0;
      #pragma unroll
      for (int c = 0; c < 16; ++c) {
        int col = (K1C + c) * 32 + lk;
        short8 vb0 = *(const short8*)(W0h + col);
        short8 vb1 = *(const short8*)(W1h + col);
        short8 ub0 = *(const short8*)(W0l + col);
        short8 ub1 = *(const short8*)(W1l + col);
        a0 = __builtin_amdgcn_mfma_f32_16x16x32_bf16(pv2[c], vb0, a0, 0, 0, 0);
        a1 = __builtin_amdgcn_mfma_f32_16x16x32_bf16(pv2[c], vb1, a1, 0, 0, 0);
        a0 = __builtin_amdgcn_mfma_f32_16x16x32_bf16(pv2[c], ub0, a0, 0, 0, 0);
        a1 = __builtin_amdgcn_mfma_f32_16x16x32_bf16(pv2[c], ub1, a1, 0, 0, 0);
      }
      // win_t and h1_t in S1: hcnt covers both (win stores drained before add)
      waitcnt8(hcnt, 8 * (t + 1));
      short8 qv[18], qu[18];
      #pragma unroll
      for (int c = 0; c < 18; ++c) {
        qv[c] = *(const short8*)(Ar + c * 32 + lk);
        qu[c] = *(const short8*)(Ar + LOOF + c * 32 + lk);
      }
      #pragma unroll
      for (int c = 0; c < 18; ++c) {
        int col = c * 32 + lk;
        short8 vb0 = *(const short8*)(W0h + col);
        short8 vb1 = *(const short8*)(W1h + col);
        short8 ub0 = *(const short8*)(W0l + col);
        short8 ub1 = *(const short8*)(W1l + col);
        a0 = __builtin_amdgcn_mfma_f32_16x16x32_bf16(qv[c], vb0, a0, 0, 0, 0);
        a1 = __builtin_amdgcn_mfma_f32_16x16x32_bf16(qv[c], vb1, a1, 0, 0, 0);
        a0 = __builtin_amdgcn_mfma_f32_16x16x32_bf16(qv[c], ub0, a0, 0, 0, 0);
        a1 = __builtin_amdgcn_mfma_f32_16x16x32_bf16(qv[c], ub1, a1, 0, 0, 0);
        a0 = __builtin_amdgcn_mfma_f32_16x16x32_bf16(qu[c], vb0, a0, 0, 0, 0);
        a1 = __builtin_amdgcn_mfma_f32_16x16x32_bf16(qu[c], vb1, a1, 0, 0, 0);
      }
      store_gsm(tid, Gsm, a0, a1);
      __syncthreads();

      {
        int ml = tid >> 2, ppi = tid & 3;
        float v[2];
        #pragma unroll
        for (int j = 0; j < 2; ++j) {
          int nl = ppi * 8 + j * 4;
          float gi = Gsm[(nl + 0) * 65 + ml] + bia[nl + 0];
          float gf = Gsm[(nl + 1) * 65 + ml] + bia[nl + 1];
          float gg = Gsm[(nl + 2) * 65 + ml] + bia[nl + 2];
          float go = Gsm[(nl + 3) * 65 + ml] + bia[nl + 3];
          float ig = 1.f / (1.f + expf(-gi));
          float fg = 1.f / (1.f + expf(-gf));
          float gt = tanhf(gg);
          float og = 1.f / (1.f + expf(-go));
          float cn = fg * creg[j] + ig * gt;
          v[j] = og * tanhf(cn);
          creg[j] = cn;
        }
        __hip_bfloat16 h0 = bhi(v[0]), h1v = bhi(v[1]);
        unsigned int* prow = (unsigned int*)(S2 + (size_t)(m0 + ml) * SLOTW);
        int dw = 288 + nt2 * 4 + ppi;      // hi dword of cols {576+nt2*8+2p, +1}
        ast(prow + dw, (unsigned int)bbits(h0) | ((unsigned int)bbits(h1v) << 16));
        if (t == T - 1) {
          int hg = nt2 * 8 + 2 * ppi;
          h2f[(m0 + ml) * H + hg]     = v[0];  c2f[(m0 + ml) * H + hg]     = creg[0];
          h2f[(m0 + ml) * H + hg + 1] = v[1];  c2f[(m0 + ml) * H + hg + 1] = creg[1];
        }
      }
      cnt_add(h2g + leaf);                  // h2 slice published
    }
  }
}

// ---------------- final GEMM: out[BT x 121] = h2 @ W2^T + b2 ----------------
__global__ __launch_bounds__(256) void k_out(
    const __hip_bfloat16* __restrict__ fxHL, const __hip_bfloat16* __restrict__ w2b,
    const float* __restrict__ b2, float* __restrict__ dout)
{
  int bid = blockIdx.x, tid = threadIdx.x;
  int mblk = bid >> 1, nblk = bid & 1;
  int wv = tid >> 6, lane = tid & 63;
  int lm = lane & 15, lk = (lane >> 4) << 3;
  int m0 = mblk * 128 + wv * 32;
  int n0 = nblk * 64;
  int r0 = m0 + lm, r1 = m0 + 16 + lm;
  const __hip_bfloat16* a0p = fxHL + (size_t)((r0 & 255) + 2) * SLOTE + (r0 >> 8) * SLOTW + 576;
  const __hip_bfloat16* a1p = fxHL + (size_t)((r1 & 255) + 2) * SLOTE + (r1 >> 8) * SLOTW + 576;
  floatx4 zz = {0.f, 0.f, 0.f, 0.f};
  floatx4 acc[2][4];
  #pragma unroll
  for (int mt = 0; mt < 2; ++mt)
    #pragma unroll
    for (int nt = 0; nt < 4; ++nt) acc[mt][nt] = zz;
  #pragma unroll
  for (int c = 0; c < 16; ++c) {
    int col = c * 32 + lk;
    short8 va0 = *(const short8*)(a0p + col);
    short8 va1 = *(const short8*)(a1p + col);
    short8 vb[4];
    #pragma unroll
    for (int nt = 0; nt < 4; ++nt)
      vb[nt] = *(const short8*)(w2b + (size_t)(n0 + nt * 16 + lm) * 512 + col);
    #pragma unroll
    for (int nt = 0; nt < 4; ++nt) {
      acc[0][nt] = __builtin_amdgcn_mfma_f32_16x16x32_bf16(va0, vb[nt], acc[0][nt], 0, 0, 0);
      acc[1][nt] = __builtin_amdgcn_mfma_f32_16x16x32_bf16(va1, vb[nt], acc[1][nt], 0, 0, 0);
    }
  }
  int rr = (lane >> 4) << 2;
  #pragma unroll
  for (int mt = 0; mt < 2; ++mt)
    #pragma unroll
    for (int nt = 0; nt < 4; ++nt)
      #pragma unroll
      for (int r = 0; r < 4; ++r) {
        int m = m0 + mt * 16 + rr + r;
        int n = n0 + nt * 16 + lm;
        if (n < OUTW) dout[(size_t)m * OUTW + n] = acc[mt][nt][r] + b2[n];
      }
}

// ---------------- host ----------------
extern "C" void kernel_launch(void* const* d_in, const int* in_sizes, int n_in,
                              void* d_out, int out_size, void* d_ws, size_t ws_size,
                              hipStream_t stream)
{
  (void)in_sizes; (void)n_in; (void)out_size; (void)ws_size;
  const float* x    = (const float*)d_in[0];
  const float* sent = (const float*)d_in[1];
  const float* h1h  = (const float*)d_in[2];
  const float* h1c  = (const float*)d_in[3];
  const float* h2h  = (const float*)d_in[4];
  const float* h2c  = (const float*)d_in[5];
  const float* Wihc = (const float*)d_in[6];
  const float* Whhc = (const float*)d_in[7];
  const float* bc   = (const float*)d_in[8];
  const float* Wihl = (const float*)d_in[9];
  const float* Whhl = (const float*)d_in[10];
  const float* bl   = (const float*)d_in[11];
  const float* W1   = (const float*)d_in[12];
  const float* b1   = (const float*)d_in[13];
  const float* W2   = (const float*)d_in[14];
  const float* b2   = (const float*)d_in[15];

  float* out = (float*)d_out;
  float* h1f = out + (size_t)B * T * OUTW;
  float* c1f = h1f + (size_t)B * H;
  float* h2f = c1f + (size_t)B * H;
  float* c2f = h2f + (size_t)B * H;

  char* p = (char*)d_ws;
  auto carve = [&](size_t bytes) { char* r = p; p += (bytes + 255) & ~(size_t)255; return r; };
  __hip_bfloat16* fxHL = (__hip_bfloat16*)carve((size_t)NSLOT * SLOTE * 2);
  __hip_bfloat16* wc1  = (__hip_bfloat16*)carve((size_t)NG * K1 * 2);
  __hip_bfloat16* wc1l = (__hip_bfloat16*)carve((size_t)NG * K1 * 2);
  __hip_bfloat16* wc2  = (__hip_bfloat16*)carve((size_t)NG * K2 * 2);
  __hip_bfloat16* wc2l = (__hip_bfloat16*)carve((size_t)NG * K2 * 2);
  __hip_bfloat16* w2b  = (__hip_bfloat16*)carve((size_t)128 * 512 * 2);
  float* bi1 = (float*)carve((size_t)NG * 4);
  float* bi2 = (float*)carve((size_t)NG * 4);
  int*   ctl = (int*)carve((size_t)2048 * 4);

  static bool attr_set = false;
  if (!attr_set) {
    (void)hipFuncSetAttribute((const void*)k_persist,
                              hipFuncAttributeMaxDynamicSharedMemorySize, LDS_SZ);
    attr_set = true;
  }

  k_pre<<<14232, 256, 0, stream>>>(x, h1h, h2h, Wihc, Whhc, bc, Wihl, Whhl, bl, W2,
                                   fxHL, wc1, wc1l, wc2, wc2l, w2b, bi1, bi2, ctl);
  k_persist<<<256, 256, LDS_SZ, stream>>>(fxHL, wc1, wc1l, wc2, wc2l, bi1, bi2,
                                          h1c, h2c, x, sent, W1, b1, ctl,
                                          h1f, c1f, h2f, c2f);
  k_out<<<512, 256, 0, stream>>>(fxHL, w2b, b2, out);
}

// Round 5
// 2670.383 us; speedup vs baseline: 1.1780x; 1.0082x over previous
//
#include <hip/hip_runtime.h>
#include <hip/hip_bf16.h>
#include <math.h>

typedef __attribute__((ext_vector_type(8))) short short8;
typedef __attribute__((ext_vector_type(4))) float floatx4;

#define DEVFN static __device__ __forceinline__

constexpr int B = 128, T = 256, H = 512;
constexpr int OUTW = 121;
// fxHL slot row layout (per batch row, per time slot), elems:
//   hi: [x(3) win(60) pad(1) h1(512) h2(512)] = 1088
//   lo: cols 0..575 only (x,win,h1)           = 576
constexpr int SLOTW = 1664;              // row stride in elems (hi 1088 + lo 576)
constexpr int LOOF  = 1088;              // lo region offset within row
constexpr int SLOTE = B * SLOTW;         // elems per time slot
constexpr int NSLOT = T + 2;
constexpr int NG  = 2048;                // 4*H gate rows (interleaved n' = hcol*4+gate)
constexpr int K1  = 576,  K1C = 18;
constexpr int K2  = 1088, K2C = 34;
constexpr int KW1P = 584, KW2P = 1096;   // LDS weight row pads

// ---- LDS offsets (bytes) ----
// G1 path. NOTE: hs/pp alias the Gsm region — window phase and GEMM phase are
// temporally disjoint (separated by barriers).
constexpr int O_WH1 = 0;                 // 32*584*2 = 37376
constexpr int O_WL1 = 37376;             // -> 74752
constexpr int O_W1S = 74752;             // 30*520*4 = 62400 -> 137152
constexpr int O_GSM = 137152;            // 32*65*4 = 8320 -> 145472
constexpr int O_HS  = 137152;            // 528*4 = 2112 (alias in Gsm)
constexpr int O_PP  = 139264;            // 240*4 = 960 (alias in Gsm)
constexpr int O_IPL = 145472;            // 30*4
constexpr int O_KL  = 145592;            // 10*4
constexpr int O_PHL = 145632;            // 64*4
constexpr int O_WAC = 145888;            // 240*4
constexpr int O_KPR = 146848;            // 10*4
constexpr int O_B1S = 146888;            // 30*4
constexpr int O_BIA = 147008;            // 32*4 -> 147136
constexpr int O_SENT = 147136;           // 64*60 fp32 = 15360 -> 162496
// G2 path:
constexpr int O_WH2 = 0;                 // 32*1096*2 = 70144
constexpr int O_WL2 = 70144;             // -> 140288
constexpr int O_GS2 = 140288;            // 8320 -> 148608
constexpr int O_BI2 = 148608;            // 128 -> 148736
constexpr int LDS_SZ = 162496;

DEVFN __hip_bfloat16 bhi(float v) { return __float2bfloat16(v); }
DEVFN __hip_bfloat16 blo(float v, __hip_bfloat16 h) { return __float2bfloat16(v - __bfloat162float(h)); }
DEVFN float bf2f(__hip_bfloat16 h) { return __bfloat162float(h); }
DEVFN unsigned short bbits(__hip_bfloat16 h) { union { __hip_bfloat16 h; unsigned short u; } c; c.h = h; return c.u; }
DEVFN unsigned int pack2(float a, float b) {
  return (unsigned int)bbits(bhi(a)) | ((unsigned int)bbits(bhi(b)) << 16);
}
DEVFN void ast(unsigned int* p, unsigned int v) {
  __hip_atomic_store(p, v, __ATOMIC_RELAXED, __HIP_MEMORY_SCOPE_AGENT);
}
DEVFN int ald(int* p) {
  return __hip_atomic_load(p, __ATOMIC_RELAXED, __HIP_MEMORY_SCOPE_AGENT);
}

// ---- 8-leaf tree-counter barriers ----
// Each barrier group = 64 blocks. Producers add to leaf (nt&7); each leaf on
// its own 128B line -> 8 serialized RMWs/line instead of 64. Consumers: 8
// threads each poll one leaf for >= 8*step.
DEVFN void waitcnt8(int* base, int target) {
  if (threadIdx.x < 8) {
    int* p = base + threadIdx.x * 32;
    int g = 0;
    while (ald(p) < target && g < (1 << 24)) { ++g; __builtin_amdgcn_s_sleep(1); }
  }
  asm volatile("" ::: "memory");
  __syncthreads();
}
// Producer (all-wave stores): drain in every wave, block-sync, then one add.
DEVFN void cnt_add(int* leaf) {
  asm volatile("s_waitcnt vmcnt(0)" ::: "memory");
  __syncthreads();
  if (threadIdx.x == 0)
    (void)__hip_atomic_fetch_add(leaf, 1, __ATOMIC_RELAXED, __HIP_MEMORY_SCOPE_AGENT);
}

// ---------------- precompute ----------------
__global__ __launch_bounds__(256) void k_pre(
    const float* __restrict__ x, const float* __restrict__ h1h, const float* __restrict__ h2h,
    const float* __restrict__ Wihc, const float* __restrict__ Whhc, const float* __restrict__ bc,
    const float* __restrict__ Wihl, const float* __restrict__ Whhl, const float* __restrict__ bl,
    const float* __restrict__ W2,
    __hip_bfloat16* __restrict__ fxHL,
    __hip_bfloat16* __restrict__ wc1, __hip_bfloat16* __restrict__ wc1l,
    __hip_bfloat16* __restrict__ wc2, __hip_bfloat16* __restrict__ wc2l,
    __hip_bfloat16* __restrict__ w2b, float* __restrict__ bi1, float* __restrict__ bi2,
    int* __restrict__ ctl)
{
  int idx = blockIdx.x * 256 + threadIdx.x;
  const int nwc1 = NG * K1, nwc2 = NG * K2, nw2b = 128 * 512, nbi = 2 * NG;
  const int nfh = B * H, nxj = T * B, nctl = 2048;
  if (idx < nwc1) {
    int n = idx / K1, col = idx - n * K1;
    int src = (n & 3) * H + (n >> 2);
    float v = (col < 63) ? Wihc[src * 63 + col]
            : (col == 63 ? 0.f : Whhc[src * 512 + (col - 64)]);
    __hip_bfloat16 h = bhi(v);
    wc1[n * K1 + col] = h; wc1l[n * K1 + col] = blo(v, h);
    return;
  }
  idx -= nwc1;
  if (idx < nwc2) {
    int n = idx / K2, col = idx - n * K2;
    int src = (n & 3) * H + (n >> 2);
    float v;
    if (col < 63)       v = Wihl[src * 575 + col];
    else if (col == 63) v = 0.f;
    else if (col < 576) v = Wihl[src * 575 + (col - 1)];
    else                v = Whhl[src * 512 + (col - 576)];
    __hip_bfloat16 h = bhi(v);
    wc2[n * K2 + col] = h; wc2l[n * K2 + col] = blo(v, h);
    return;
  }
  idx -= nwc2;
  if (idx < nw2b) {
    int n = idx >> 9, col = idx & 511;
    w2b[idx] = bhi(n < OUTW ? W2[n * 512 + col] : 0.f);
    return;
  }
  idx -= nw2b;
  if (idx < nbi) {
    int n = idx & (NG - 1);
    int src = (n & 3) * H + (n >> 2);
    if (idx < NG) bi1[n] = bc[src]; else bi2[n] = bl[src];
    return;
  }
  idx -= nbi;
  if (idx < nfh) {  // slot0 h1 init (hi+lo)
    int b = idx >> 9, j = idx & 511;
    float v = h1h[idx];
    __hip_bfloat16 h = bhi(v);
    fxHL[b * SLOTW + 64 + j] = h;
    fxHL[b * SLOTW + LOOF + 64 + j] = blo(v, h);
    return;
  }
  idx -= nfh;
  if (idx < nfh) {  // slot1 h2 init (hi only)
    int b = idx >> 9, j = idx & 511;
    fxHL[(size_t)SLOTE + b * SLOTW + 576 + j] = bhi(h2h[idx]);
    return;
  }
  idx -= nfh;
  if (idx < nxj) {  // x cols {0,1} hi + lo zeros for slot t+1
    int t = idx >> 7, b = idx & 127;
    float x0 = x[(b * T + t) * 3 + 0], x1 = x[(b * T + t) * 3 + 1];
    unsigned int* ph = (unsigned int*)(fxHL + (size_t)(t + 1) * SLOTE + b * SLOTW);
    ph[0] = pack2(x0, x1);
    unsigned int* pl = (unsigned int*)(fxHL + (size_t)(t + 1) * SLOTE + b * SLOTW + LOOF);
    pl[0] = 0u;
    return;
  }
  idx -= nxj;
  if (idx < nctl) ctl[idx] = 0;
}

// ---------------- MFMA helper (A rows from global, W in LDS) ----------------
template <int KWP>
DEVFN void gemm3(int tid, const __hip_bfloat16* __restrict__ Aslot, int m0,
                 const __hip_bfloat16* __restrict__ Wh, const __hip_bfloat16* __restrict__ Wl,
                 int cbeg, int cend, floatx4& a0, floatx4& a1)
{
  const int lane = tid & 63, wv = tid >> 6;
  const int lm = lane & 15, lk = (lane >> 4) << 3;
  const __hip_bfloat16* Ar = Aslot + (size_t)(m0 + wv * 16 + lm) * SLOTW;
  const __hip_bfloat16* W0h = Wh + lm * KWP;
  const __hip_bfloat16* W1h = Wh + (16 + lm) * KWP;
  const __hip_bfloat16* W0l = Wl + lm * KWP;
  const __hip_bfloat16* W1l = Wl + (16 + lm) * KWP;
  #pragma unroll 4
  for (int c = cbeg; c < cend; ++c) {
    int col = c * 32 + lk;
    short8 va  = *(const short8*)(Ar + col);
    short8 ua  = *(const short8*)(Ar + LOOF + col);
    short8 vb0 = *(const short8*)(W0h + col);
    short8 vb1 = *(const short8*)(W1h + col);
    short8 ub0 = *(const short8*)(W0l + col);
    short8 ub1 = *(const short8*)(W1l + col);
    a0 = __builtin_amdgcn_mfma_f32_16x16x32_bf16(va, vb0, a0, 0, 0, 0);
    a1 = __builtin_amdgcn_mfma_f32_16x16x32_bf16(va, vb1, a1, 0, 0, 0);
    a0 = __builtin_amdgcn_mfma_f32_16x16x32_bf16(va, ub0, a0, 0, 0, 0);
    a1 = __builtin_amdgcn_mfma_f32_16x16x32_bf16(va, ub1, a1, 0, 0, 0);
    a0 = __builtin_amdgcn_mfma_f32_16x16x32_bf16(ua, vb0, a0, 0, 0, 0);
    a1 = __builtin_amdgcn_mfma_f32_16x16x32_bf16(ua, vb1, a1, 0, 0, 0);
  }
}

DEVFN void store_gsm(int tid, float* Gsm, floatx4 a0, floatx4 a1) {
  const int lane = tid & 63, wv = tid >> 6;
  const int lm = lane & 15, rr = (lane >> 4) << 2;
  #pragma unroll
  for (int r = 0; r < 4; ++r) {
    Gsm[lm * 65 + wv * 16 + rr + r]        = a0[r];
    Gsm[(16 + lm) * 65 + wv * 16 + rr + r] = a1[r];
  }
}

// ---------------- persistent fused kernel ----------------
__global__ __launch_bounds__(256, 1) void k_persist(
    __hip_bfloat16* __restrict__ fxHL,
    const __hip_bfloat16* __restrict__ wc1, const __hip_bfloat16* __restrict__ wc1l,
    const __hip_bfloat16* __restrict__ wc2, const __hip_bfloat16* __restrict__ wc2l,
    const float* __restrict__ bi1, const float* __restrict__ bi2,
    const float* __restrict__ c1init, const float* __restrict__ c2init,
    const float* __restrict__ xin, const float* __restrict__ sent,
    const float* __restrict__ W1, const float* __restrict__ b1,
    int* __restrict__ ctl,
    float* __restrict__ h1f, float* __restrict__ c1f,
    float* __restrict__ h2f, float* __restrict__ c2f)
{
  extern __shared__ char sm[];
  const int gid = blockIdx.x, tid = threadIdx.x;
  const int lane = tid & 63, wv = tid >> 6;
  const int lm = lane & 15, lk = (lane >> 4) << 3;

  if (gid < 128) {
    // ========== G1: window + lstm1 ==========
    const int nt1 = gid >> 1, mh = gid & 1;
    const int n0 = nt1 * 32, m0 = mh * 64;
    const int brow = mh * 64 + nt1;
    const int leaf = (nt1 & 7) * 32;
    int* hcnt = ctl + mh * 256;            // h1 step completion tree (8 leaves)
    int* wcnt = ctl + 512 + mh * 256;      // win publication tree
    __hip_bfloat16* smWh = (__hip_bfloat16*)(sm + O_WH1);
    __hip_bfloat16* smWl = (__hip_bfloat16*)(sm + O_WL1);
    float* smW1 = (float*)(sm + O_W1S);
    float* Gsm  = (float*)(sm + O_GSM);
    float* hs   = (float*)(sm + O_HS);   // aliases Gsm region (window phase only)
    float* pp   = (float*)(sm + O_PP);   // aliases Gsm region (window phase only)
    float* ipl  = (float*)(sm + O_IPL);
    float* kl   = (float*)(sm + O_KL);
    float* phl  = (float*)(sm + O_PHL);
    float* wac  = (float*)(sm + O_WAC);
    float* kpr  = (float*)(sm + O_KPR);
    float* b1s  = (float*)(sm + O_B1S);
    float* bia  = (float*)(sm + O_BIA);
    float* ssent = (float*)(sm + O_SENT);

    for (int i = tid; i < 32 * 72; i += 256) {
      int r = i / 72, c8 = (i - r * 72) * 8;
      *(short8*)(smWh + r * KW1P + c8) = *(const short8*)(wc1  + (size_t)(n0 + r) * K1 + c8);
      *(short8*)(smWl + r * KW1P + c8) = *(const short8*)(wc1l + (size_t)(n0 + r) * K1 + c8);
    }
    for (int i = tid; i < 30 * 512; i += 256) {
      int j = i >> 9, c = i & 511;
      smW1[j * 520 + (c >> 6) * 65 + (c & 63)] = W1[i];
    }
    for (int i = tid; i < 64 * 60; i += 256)
      ssent[i] = sent[(size_t)brow * 64 * 60 + i];   // fp32 — bf16 here fails c1f (R7)
    if (tid < 30) b1s[tid] = b1[tid];
    if (tid < 10) kpr[tid] = 0.f;
    if (tid < 32) bia[tid] = bi1[n0 + tid];
    __syncthreads();

    float creg[2];
    {
      int ml = tid >> 2, ppi = tid & 3;
      creg[0] = c1init[(m0 + ml) * H + nt1 * 8 + 2 * ppi + 0];
      creg[1] = c1init[(m0 + ml) * H + nt1 * 8 + 2 * ppi + 1];
    }

    const __hip_bfloat16* W0h = smWh + lm * KW1P;
    const __hip_bfloat16* W1h = smWh + (16 + lm) * KW1P;
    const __hip_bfloat16* W0l = smWl + lm * KW1P;
    const __hip_bfloat16* W1l = smWl + (16 + lm) * KW1P;

    for (int t = 0; t < T; ++t) {
      __hip_bfloat16* S1 = fxHL + (size_t)(t + 1) * SLOTE;
      __hip_bfloat16* S0 = fxHL + (size_t)t * SLOTE;

      waitcnt8(hcnt, 8 * t);   // all same-half h1_{t-1} published

      // ---- own h-row loads + x scalar, then register A-prefetch ----
      // PREFETCH PLACEMENT IS LOAD-BEARING (R3 lesson): waves 1-3 issue
      // pva/pua HERE so the loads fly under the window phase and stay in
      // VGPRs. Wave 0 (the win-publishing wave) defers its prefetch until
      // AFTER its win flag add: otherwise wave 0's `s_waitcnt vmcnt(0)`
      // before the flag waits for the whole 32KB prefetch burst, delaying
      // every peer's win-wait (R4 post-mortem theory).
      const __hip_bfloat16* wrow = S0 + (size_t)brow * SLOTW;
      __hip_bfloat16 a0h = wrow[64 + tid];
      __hip_bfloat16 a0l = wrow[LOOF + 64 + tid];
      __hip_bfloat16 a1h = wrow[64 + 256 + tid];
      __hip_bfloat16 a1l = wrow[LOOF + 64 + 256 + tid];
      float x2v = xin[(brow * T + t) * 3 + 2];
      const __hip_bfloat16* Ar = S0 + (size_t)(m0 + wv * 16 + lm) * SLOTW;
      short8 pva[16], pua[16];
      if (wv != 0) {
        #pragma unroll
        for (int c = 0; c < 16; ++c) {
          pva[c] = *(const short8*)(Ar + (c + 2) * 32 + lk);
          pua[c] = *(const short8*)(Ar + LOOF + (c + 2) * 32 + lk);
        }
      }
      hs[(tid >> 6) * 66 + (tid & 63)] = bf2f(a0h) + bf2f(a0l);
      hs[((tid + 256) >> 6) * 66 + (tid & 63)] = bf2f(a1h) + bf2f(a1l);
      __syncthreads();

      // ---- window compute (LDS only; waves 1-3 A-prefetch in flight) ----
      if (tid < 240) {
        int j = tid >> 3, p = tid & 7;
        const float* wp = smW1 + j * 520 + p * 65;
        const float* hv = hs + p * 66;
        float s = 0.f;
        #pragma unroll 8
        for (int k = 0; k < 64; ++k) s += hv[k] * wp[k];
        pp[tid] = s;
      }
      __syncthreads();
      if (tid < 30) {       // merged ip-exp + kappa stage (wave 0 only)
        float s = b1s[tid];
        #pragma unroll
        for (int p = 0; p < 8; ++p) s += pp[tid * 8 + p];
        float e = expf(s);
        ipl[tid] = e;
        if (tid >= 20) {
          float kap = e - kpr[tid - 20];
          kpr[tid - 20] = kap; kl[tid - 20] = kap;
        }
      }
      // wave-local hand-off (both stages wave 0): LDS writes complete, no
      // block barrier needed; "memory" clobber pins the ds op order.
      asm volatile("s_waitcnt lgkmcnt(0)" ::: "memory");
      if (tid < 64) {
        float u = (float)(tid + 1);
        float acc = 0.f;
        #pragma unroll
        for (int k = 0; k < 10; ++k) {
          float d = kl[k] - u;
          acc += ipl[k] * expf(-ipl[10 + k] * d * d);
        }
        phl[tid] = acc;
      }
      __syncthreads();
      if (tid < 240) {
        int c = tid >> 2, p = tid & 3;
        float acc = 0.f;
        #pragma unroll
        for (int s0 = 0; s0 < 16; ++s0)
          acc += phl[p * 16 + s0] * ssent[(p * 16 + s0) * 60 + c];
        wac[tid] = acc;
      }
      __syncthreads();
      if (tid < 31) {  // publish win; winv reduction folded in (8 adds/thread)
        int d = 1 + tid;
        int c0 = 2 * d, c1 = 2 * d + 1;
        float v0, v1;
        if (c0 == 2) v0 = x2v;
        else { int j = (c0 - 3) * 4; v0 = wac[j] + wac[j + 1] + wac[j + 2] + wac[j + 3]; }
        if (c1 == 63) v1 = 0.f;
        else { int j = (c1 - 3) * 4; v1 = wac[j] + wac[j + 1] + wac[j + 2] + wac[j + 3]; }
        __hip_bfloat16 h0 = bhi(v0), h1v = bhi(v1);
        unsigned int* prow = (unsigned int*)(S1 + (size_t)brow * SLOTW);
        ast(prow + d, (unsigned int)bbits(h0) | ((unsigned int)bbits(h1v) << 16));
        ast(prow + (LOOF >> 1) + d,
            (unsigned int)bbits(blo(v0, h0)) | ((unsigned int)bbits(blo(v1, h1v)) << 16));
      }
      // win flag: wave-0-only protocol. All win stores are wave 0's, so only
      // wave 0 drains; no block barrier. Then wave 0 issues its deferred
      // A-prefetch (its h-MFMA tail overlaps the win hop).
      if (wv == 0) {
        asm volatile("s_waitcnt vmcnt(0)" ::: "memory");
        if (tid == 0)
          (void)__hip_atomic_fetch_add(wcnt + leaf, 1, __ATOMIC_RELAXED,
                                       __HIP_MEMORY_SCOPE_AGENT);
        #pragma unroll
        for (int c = 0; c < 16; ++c) {
          pva[c] = *(const short8*)(Ar + (c + 2) * 32 + lk);
          pua[c] = *(const short8*)(Ar + LOOF + (c + 2) * 32 + lk);
        }
      }

      // ---- h1-part MFMA from prefetched registers (no global loads) ----
      floatx4 a0 = {0.f, 0.f, 0.f, 0.f}, a1 = a0;
      #pragma unroll
      for (int c = 0; c < 16; ++c) {
        int col = (c + 2) * 32 + lk;
        short8 vb0 = *(const short8*)(W0h + col);
        short8 vb1 = *(const short8*)(W1h + col);
        short8 ub0 = *(const short8*)(W0l + col);
        short8 ub1 = *(const short8*)(W1l + col);
        a0 = __builtin_amdgcn_mfma_f32_16x16x32_bf16(pva[c], vb0, a0, 0, 0, 0);
        a1 = __builtin_amdgcn_mfma_f32_16x16x32_bf16(pva[c], vb1, a1, 0, 0, 0);
        a0 = __builtin_amdgcn_mfma_f32_16x16x32_bf16(pva[c], ub0, a0, 0, 0, 0);
        a1 = __builtin_amdgcn_mfma_f32_16x16x32_bf16(pva[c], ub1, a1, 0, 0, 0);
        a0 = __builtin_amdgcn_mfma_f32_16x16x32_bf16(pua[c], vb0, a0, 0, 0, 0);
        a1 = __builtin_amdgcn_mfma_f32_16x16x32_bf16(pua[c], vb1, a1, 0, 0, 0);
      }
      waitcnt8(wcnt, 8 * (t + 1));          // all wins of this half available
      gemm3<KW1P>(tid, S1, m0, smWh, smWl, 0, 2, a0, a1);
      store_gsm(tid, Gsm, a0, a1);
      __syncthreads();

      // ---- epilogue: each thread 2 adjacent h-cols of one m-row ----
      {
        int ml = tid >> 2, ppi = tid & 3;
        float v[2];
        #pragma unroll
        for (int j = 0; j < 2; ++j) {
          int nl = ppi * 8 + j * 4;
          float gi = Gsm[(nl + 0) * 65 + ml] + bia[nl + 0];
          float gf = Gsm[(nl + 1) * 65 + ml] + bia[nl + 1];
          float gg = Gsm[(nl + 2) * 65 + ml] + bia[nl + 2];
          float go = Gsm[(nl + 3) * 65 + ml] + bia[nl + 3];
          float ig = 1.f / (1.f + expf(-gi));
          float fg = 1.f / (1.f + expf(-gf));
          float gt = tanhf(gg);
          float og = 1.f / (1.f + expf(-go));
          float cn = fg * creg[j] + ig * gt;
          v[j] = og * tanhf(cn);
          creg[j] = cn;
        }
        __hip_bfloat16 h0 = bhi(v[0]), h1v = bhi(v[1]);
        unsigned int* prow = (unsigned int*)(S1 + (size_t)(m0 + ml) * SLOTW);
        int dw = 32 + nt1 * 4 + ppi;       // hi dword of cols {64+nt1*8+2p, +1}
        ast(prow + dw, (unsigned int)bbits(h0) | ((unsigned int)bbits(h1v) << 16));
        ast(prow + (LOOF >> 1) + dw,
            (unsigned int)bbits(blo(v[0], h0)) | ((unsigned int)bbits(blo(v[1], h1v)) << 16));
        if (t == T - 1) {
          int hg = nt1 * 8 + 2 * ppi;
          h1f[(m0 + ml) * H + hg]     = v[0];  c1f[(m0 + ml) * H + hg]     = creg[0];
          h1f[(m0 + ml) * H + hg + 1] = v[1];  c1f[(m0 + ml) * H + hg + 1] = creg[1];
        }
      }
      cnt_add(hcnt + leaf);                 // h1 slice published (drains win+h)
    }
  } else {
    // ========== G2: lstm2 ==========
    const int g = gid - 128;
    const int nt2 = g >> 1, mh = g & 1;
    const int n0 = nt2 * 32, m0 = mh * 64;
    const int leaf = (nt2 & 7) * 32;
    int* hcnt = ctl + mh * 256;
    int* h2g  = ctl + 1024 + mh * 256;
    __hip_bfloat16* smWh = (__hip_bfloat16*)(sm + O_WH2);
    __hip_bfloat16* smWl = (__hip_bfloat16*)(sm + O_WL2);
    float* Gsm = (float*)(sm + O_GS2);
    float* bia = (float*)(sm + O_BI2);

    for (int i = tid; i < 32 * 136; i += 256) {
      int r = i / 136, c8 = (i - r * 136) * 8;
      *(short8*)(smWh + r * KW2P + c8) = *(const short8*)(wc2  + (size_t)(n0 + r) * K2 + c8);
      *(short8*)(smWl + r * KW2P + c8) = *(const short8*)(wc2l + (size_t)(n0 + r) * K2 + c8);
    }
    if (tid < 32) bia[tid] = bi2[n0 + tid];
    __syncthreads();

    float creg[2];
    {
      int ml = tid >> 2, ppi = tid & 3;
      creg[0] = c2init[(m0 + ml) * H + nt2 * 8 + 2 * ppi + 0];
      creg[1] = c2init[(m0 + ml) * H + nt2 * 8 + 2 * ppi + 1];
    }

    const __hip_bfloat16* W0h = smWh + lm * KW2P;
    const __hip_bfloat16* W1h = smWh + (16 + lm) * KW2P;
    const __hip_bfloat16* W0l = smWl + lm * KW2P;
    const __hip_bfloat16* W1l = smWl + (16 + lm) * KW2P;

    for (int t = 0; t < T; ++t) {
      __hip_bfloat16* S1 = fxHL + (size_t)(t + 1) * SLOTE;
      __hip_bfloat16* S2 = fxHL + (size_t)(t + 2) * SLOTE;
      const __hip_bfloat16* Ar = S1 + (size_t)(m0 + wv * 16 + lm) * SLOTW;

      // own-half h2_{t-1} complete in S1 -> prefetch h2-part A (hi only)
      waitcnt8(h2g, 8 * t);
      short8 pv2[16];
      #pragma unroll
      for (int c = 0; c < 16; ++c)
        pv2[c] = *(const short8*)(Ar + (K1C + c) * 32 + lk);
      floatx4 a0 = {0.f, 0.f, 0.f, 0.f}, a1 = a0;
      #pragma unroll
      for (int c = 0; c < 16; ++c) {
        int col = (K1C + c) * 32 + lk;
        short8 vb0 = *(const short8*)(W0h + col);
        short8 vb1 = *(const short8*)(W1h + col);
        short8 ub0 = *(const short8*)(W0l + col);
        short8 ub1 = *(const short8*)(W1l + col);
        a0 = __builtin_amdgcn_mfma_f32_16x16x32_bf16(pv2[c], vb0, a0, 0, 0, 0);
        a1 = __builtin_amdgcn_mfma_f32_16x16x32_bf16(pv2[c], vb1, a1, 0, 0, 0);
        a0 = __builtin_amdgcn_mfma_f32_16x16x32_bf16(pv2[c], ub0, a0, 0, 0, 0);
        a1 = __builtin_amdgcn_mfma_f32_16x16x32_bf16(pv2[c], ub1, a1, 0, 0, 0);
      }
      // win_t and h1_t in S1: hcnt covers both (win stores drained before add)
      waitcnt8(hcnt, 8 * (t + 1));
      short8 qv[18], qu[18];
      #pragma unroll
      for (int c = 0; c < 18; ++c) {
        qv[c] = *(const short8*)(Ar + c * 32 + lk);
        qu[c] = *(const short8*)(Ar + LOOF + c * 32 + lk);
      }
      #pragma unroll
      for (int c = 0; c < 18; ++c) {
        int col = c * 32 + lk;
        short8 vb0 = *(const short8*)(W0h + col);
        short8 vb1 = *(const short8*)(W1h + col);
        short8 ub0 = *(const short8*)(W0l + col);
        short8 ub1 = *(const short8*)(W1l + col);
        a0 = __builtin_amdgcn_mfma_f32_16x16x32_bf16(qv[c], vb0, a0, 0, 0, 0);
        a1 = __builtin_amdgcn_mfma_f32_16x16x32_bf16(qv[c], vb1, a1, 0, 0, 0);
        a0 = __builtin_amdgcn_mfma_f32_16x16x32_bf16(qv[c], ub0, a0, 0, 0, 0);
        a1 = __builtin_amdgcn_mfma_f32_16x16x32_bf16(qv[c], ub1, a1, 0, 0, 0);
        a0 = __builtin_amdgcn_mfma_f32_16x16x32_bf16(qu[c], vb0, a0, 0, 0, 0);
        a1 = __builtin_amdgcn_mfma_f32_16x16x32_bf16(qu[c], vb1, a1, 0, 0, 0);
      }
      store_gsm(tid, Gsm, a0, a1);
      __syncthreads();

      {
        int ml = tid >> 2, ppi = tid & 3;
        float v[2];
        #pragma unroll
        for (int j = 0; j < 2; ++j) {
          int nl = ppi * 8 + j * 4;
          float gi = Gsm[(nl + 0) * 65 + ml] + bia[nl + 0];
          float gf = Gsm[(nl + 1) * 65 + ml] + bia[nl + 1];
          float gg = Gsm[(nl + 2) * 65 + ml] + bia[nl + 2];
          float go = Gsm[(nl + 3) * 65 + ml] + bia[nl + 3];
          float ig = 1.f / (1.f + expf(-gi));
          float fg = 1.f / (1.f + expf(-gf));
          float gt = tanhf(gg);
          float og = 1.f / (1.f + expf(-go));
          float cn = fg * creg[j] + ig * gt;
          v[j] = og * tanhf(cn);
          creg[j] = cn;
        }
        __hip_bfloat16 h0 = bhi(v[0]), h1v = bhi(v[1]);
        unsigned int* prow = (unsigned int*)(S2 + (size_t)(m0 + ml) * SLOTW);
        int dw = 288 + nt2 * 4 + ppi;      // hi dword of cols {576+nt2*8+2p, +1}
        ast(prow + dw, (unsigned int)bbits(h0) | ((unsigned int)bbits(h1v) << 16));
        if (t == T - 1) {
          int hg = nt2 * 8 + 2 * ppi;
          h2f[(m0 + ml) * H + hg]     = v[0];  c2f[(m0 + ml) * H + hg]     = creg[0];
          h2f[(m0 + ml) * H + hg + 1] = v[1];  c2f[(m0 + ml) * H + hg + 1] = creg[1];
        }
      }
      cnt_add(h2g + leaf);                  // h2 slice published
    }
  }
}

// ---------------- final GEMM: out[BT x 121] = h2 @ W2^T + b2 ----------------
__global__ __launch_bounds__(256) void k_out(
    const __hip_bfloat16* __restrict__ fxHL, const __hip_bfloat16* __restrict__ w2b,
    const float* __restrict__ b2, float* __restrict__ dout)
{
  int bid = blockIdx.x, tid = threadIdx.x;
  int mblk = bid >> 1, nblk = bid & 1;
  int wv = tid >> 6, lane = tid & 63;
  int lm = lane & 15, lk = (lane >> 4) << 3;
  int m0 = mblk * 128 + wv * 32;
  int n0 = nblk * 64;
  int r0 = m0 + lm, r1 = m0 + 16 + lm;
  const __hip_bfloat16* a0p = fxHL + (size_t)((r0 & 255) + 2) * SLOTE + (r0 >> 8) * SLOTW + 576;
  const __hip_bfloat16* a1p = fxHL + (size_t)((r1 & 255) + 2) * SLOTE + (r1 >> 8) * SLOTW + 576;
  floatx4 zz = {0.f, 0.f, 0.f, 0.f};
  floatx4 acc[2][4];
  #pragma unroll
  for (int mt = 0; mt < 2; ++mt)
    #pragma unroll
    for (int nt = 0; nt < 4; ++nt) acc[mt][nt] = zz;
  #pragma unroll
  for (int c = 0; c < 16; ++c) {
    int col = c * 32 + lk;
    short8 va0 = *(const short8*)(a0p + col);
    short8 va1 = *(const short8*)(a1p + col);
    short8 vb[4];
    #pragma unroll
    for (int nt = 0; nt < 4; ++nt)
      vb[nt] = *(const short8*)(w2b + (size_t)(n0 + nt * 16 + lm) * 512 + col);
    #pragma unroll
    for (int nt = 0; nt < 4; ++nt) {
      acc[0][nt] = __builtin_amdgcn_mfma_f32_16x16x32_bf16(va0, vb[nt], acc[0][nt], 0, 0, 0);
      acc[1][nt] = __builtin_amdgcn_mfma_f32_16x16x32_bf16(va1, vb[nt], acc[1][nt], 0, 0, 0);
    }
  }
  int rr = (lane >> 4) << 2;
  #pragma unroll
  for (int mt = 0; mt < 2; ++mt)
    #pragma unroll
    for (int nt = 0; nt < 4; ++nt)
      #pragma unroll
      for (int r = 0; r < 4; ++r) {
        int m = m0 + mt * 16 + rr + r;
        int n = n0 + nt * 16 + lm;
        if (n < OUTW) dout[(size_t)m * OUTW + n] = acc[mt][nt][r] + b2[n];
      }
}

// ---------------- host ----------------
extern "C" void kernel_launch(void* const* d_in, const int* in_sizes, int n_in,
                              void* d_out, int out_size, void* d_ws, size_t ws_size,
                              hipStream_t stream)
{
  (void)in_sizes; (void)n_in; (void)out_size; (void)ws_size;
  const float* x    = (const float*)d_in[0];
  const float* sent = (const float*)d_in[1];
  const float* h1h  = (const float*)d_in[2];
  const float* h1c  = (const float*)d_in[3];
  const float* h2h  = (const float*)d_in[4];
  const float* h2c  = (const float*)d_in[5];
  const float* Wihc = (const float*)d_in[6];
  const float* Whhc = (const float*)d_in[7];
  const float* bc   = (const float*)d_in[8];
  const float* Wihl = (const float*)d_in[9];
  const float* Whhl = (const float*)d_in[10];
  const float* bl   = (const float*)d_in[11];
  const float* W1   = (const float*)d_in[12];
  const float* b1   = (const float*)d_in[13];
  const float* W2   = (const float*)d_in[14];
  const float* b2   = (const float*)d_in[15];

  float* out = (float*)d_out;
  float* h1f = out + (size_t)B * T * OUTW;
  float* c1f = h1f + (size_t)B * H;
  float* h2f = c1f + (size_t)B * H;
  float* c2f = h2f + (size_t)B * H;

  char* p = (char*)d_ws;
  auto carve = [&](size_t bytes) { char* r = p; p += (bytes + 255) & ~(size_t)255; return r; };
  __hip_bfloat16* fxHL = (__hip_bfloat16*)carve((size_t)NSLOT * SLOTE * 2);
  __hip_bfloat16* wc1  = (__hip_bfloat16*)carve((size_t)NG * K1 * 2);
  __hip_bfloat16* wc1l = (__hip_bfloat16*)carve((size_t)NG * K1 * 2);
  __hip_bfloat16* wc2  = (__hip_bfloat16*)carve((size_t)NG * K2 * 2);
  __hip_bfloat16* wc2l = (__hip_bfloat16*)carve((size_t)NG * K2 * 2);
  __hip_bfloat16* w2b  = (__hip_bfloat16*)carve((size_t)128 * 512 * 2);
  float* bi1 = (float*)carve((size_t)NG * 4);
  float* bi2 = (float*)carve((size_t)NG * 4);
  int*   ctl = (int*)carve((size_t)2048 * 4);

  static bool attr_set = false;
  if (!attr_set) {
    (void)hipFuncSetAttribute((const void*)k_persist,
                              hipFuncAttributeMaxDynamicSharedMemorySize, LDS_SZ);
    attr_set = true;
  }

  k_pre<<<14232, 256, 0, stream>>>(x, h1h, h2h, Wihc, Whhc, bc, Wihl, Whhl, bl, W2,
                                   fxHL, wc1, wc1l, wc2, wc2l, w2b, bi1, bi2, ctl);
  k_persist<<<256, 256, LDS_SZ, stream>>>(fxHL, wc1, wc1l, wc2, wc2l, bi1, bi2,
                                          h1c, h2c, x, sent, W1, b1, ctl,
                                          h1f, c1f, h2f, c2f);
  k_out<<<512, 256, 0, stream>>>(fxHL, w2b, b2, out);
}